// Round 5
// baseline (778.561 us; speedup 1.0000x reference)
//
#include <hip/hip_runtime.h>
#include <hip/hip_bf16.h>

#define NN 50000
#define EE 640000
#define HD 128
#define NCLS 40
#define BN_EPS 1e-5f
#define TROWS 32
#define NT32 1563  // ceil(NN/32)

typedef short bf16x8 __attribute__((ext_vector_type(8)));
typedef float f32x4 __attribute__((ext_vector_type(4)));

__device__ __forceinline__ short f2bf(float f) {
    __hip_bfloat16 h = __float2bfloat16(f);
    return *reinterpret_cast<short*>(&h);
}
__device__ __forceinline__ float bflo(unsigned int v) { return __uint_as_float(v << 16); }
__device__ __forceinline__ float bfhi(unsigned int v) { return __uint_as_float(v & 0xffff0000u); }

// ---------------- edge_index width detect + decode (+degree count) ----------------
__global__ void detect_kernel(const void* __restrict__ ei, int* __restrict__ flag) {
    int t = threadIdx.x;  // 256
    const long long* p = (const long long*)ei;
    long long v = p[(size_t)t * (EE / 256)];
    if (v < 0 || v >= NN) atomicOr(flag, 1);  // flag=1 -> int32 data
}

__global__ void decode_deg_kernel(const void* __restrict__ ei, const int* __restrict__ flag,
                                  int* __restrict__ src, int* __restrict__ dst,
                                  int* __restrict__ deg) {
    bool narrow = (*flag != 0);
    for (int e = blockIdx.x * blockDim.x + threadIdx.x; e < EE; e += gridDim.x * blockDim.x) {
        int s, d;
        if (narrow) {
            const int* p = (const int*)ei;
            s = p[e]; d = p[EE + e];
        } else {
            const long long* p = (const long long*)ei;
            s = (int)p[e]; d = (int)p[EE + e];
        }
        src[e] = s;
        dst[e] = d;
        atomicAdd(&deg[d], 1);
    }
}

// ---------------- parallel scan: deg -> rowptr, invdeg ----------------
__global__ void deg_blocksum(const int* __restrict__ deg, int* __restrict__ bsum) {
    int i = blockIdx.x * 256 + threadIdx.x;
    int d = (i < NN) ? deg[i] : 0;
#pragma unroll
    for (int o = 32; o; o >>= 1) d += __shfl_down(d, o);
    __shared__ int ws[4];
    if ((threadIdx.x & 63) == 0) ws[threadIdx.x >> 6] = d;
    __syncthreads();
    if (threadIdx.x == 0) bsum[blockIdx.x] = ws[0] + ws[1] + ws[2] + ws[3];
}

__global__ void scan_bsums(const int* __restrict__ bsum, int* __restrict__ boff) {
    __shared__ int s[256];
    int t = threadIdx.x;
    int v = (t < 196) ? bsum[t] : 0;
    s[t] = v;
    __syncthreads();
    for (int o = 1; o < 256; o <<= 1) {
        int u = (t >= o) ? s[t - o] : 0;
        __syncthreads();
        s[t] += u;
        __syncthreads();
    }
    if (t < 196) boff[t] = s[t] - v;  // exclusive
}

__global__ void rowptr_fill(const int* __restrict__ deg, const int* __restrict__ boff,
                            int* __restrict__ rowptr, float* __restrict__ invdeg) {
    int b = blockIdx.x, t = threadIdx.x, i = b * 256 + t;
    int d = (i < NN) ? deg[i] : 0;
    __shared__ int s[256];
    s[t] = d;
    __syncthreads();
    for (int o = 1; o < 256; o <<= 1) {
        int u = (t >= o) ? s[t - o] : 0;
        __syncthreads();
        s[t] += u;
        __syncthreads();
    }
    int excl = s[t] - d + boff[b];
    if (i < NN) {
        rowptr[i] = excl;
        invdeg[i] = 1.0f / (float)(d > 1 ? d : 1);
        if (i == NN - 1) rowptr[NN] = excl + d;
    }
}

__global__ void fill_kernel(const int* __restrict__ src, const int* __restrict__ dst,
                            const int* __restrict__ rowptr, int* __restrict__ cursor,
                            int* __restrict__ adj) {
    for (int e = blockIdx.x * blockDim.x + threadIdx.x; e < EE; e += gridDim.x * blockDim.x) {
        int d = dst[e];
        int pos = atomicAdd(&cursor[d], 1);
        adj[rowptr[d] + pos] = src[e];
    }
}

// ---------------- weights: Wc[which] = bf16(W_w @ lin_{l/r}[layer]); fc0 -> bf16 ----------------
__global__ void combine_w(const float* __restrict__ Ww, const float* __restrict__ linl,
                          const float* __restrict__ linr, ushort* __restrict__ Wcb) {
    int k = threadIdx.x;
    int m = blockIdx.x;
    int which = blockIdx.y;  // layer = which>>1, l/r = which&1
    const float* lin = ((which & 1) ? linr : linl) + (which >> 1) * HD * HD;
    __shared__ float wrow[HD];
    wrow[k] = Ww[m * HD + k];
    __syncthreads();
    float acc = 0.f;
    for (int j = 0; j < HD; ++j) acc += wrow[j] * lin[j * HD + k];
    Wcb[which * HD * HD + m * HD + k] = (unsigned short)f2bf(acc);
}

__global__ void convw_kernel(const float* __restrict__ W, ushort* __restrict__ Wb) {
    int i = blockIdx.x * 256 + threadIdx.x;
    if (i < HD * HD) Wb[i] = (unsigned short)f2bf(W[i]);
}

// ---------------- MFMA GEMM (swapped operands, wave-sliced columns, 32-row tiles) ---------
// Y[n,m] = sum_k A1[n,k]*W1[m,k] (+ A2[n,k]*W2[m,k]); per-column stats fused; no bias
// (BatchNorm cancels additive per-column constants). Wave wv owns cols [wv*32, wv*32+32).
// mfma(a=Wfrag, b=Xfrag): D col(lane&15)=X row, D regs = 4 consecutive Y cols -> f32x4 store.
template <bool DUAL, bool F32A>
__global__ __launch_bounds__(256, 3) void gemm_mfma(const void* __restrict__ A1,
                                                    const void* __restrict__ A2,
                                                    const ushort* __restrict__ W1,
                                                    const ushort* __restrict__ W2,
                                                    float* __restrict__ Y,
                                                    float* __restrict__ stats) {
    int t = threadIdx.x;
    int l = t & 63, wv = t >> 6;
    int lr = l & 15, lg = l >> 4;

    // B-operand fragments (weights): wave's column slice, c_global = wv*2 + cc
    bf16x8 bf1[2][4], bf2[2][4];
#pragma unroll
    for (int cc = 0; cc < 2; ++cc)
#pragma unroll
        for (int kk = 0; kk < 4; ++kk) {
            int wrow = (wv * 2 + cc) * 16 + lr;
            bf1[cc][kk] = *reinterpret_cast<const bf16x8*>(W1 + (size_t)wrow * HD + kk * 32 + lg * 8);
            if (DUAL)
                bf2[cc][kk] = *reinterpret_cast<const bf16x8*>(W2 + (size_t)wrow * HD + kk * 32 + lg * 8);
        }

    f32x4 ss[2] = {}, sq[2] = {};

    for (int tile = blockIdx.x; tile < NT32; tile += gridDim.x) {
        int rbase = tile * TROWS;
        // load ALL A-fragments for this tile upfront (max outstanding loads)
        bf16x8 a1[2][4], a2[2][4];
#pragma unroll
        for (int rf = 0; rf < 2; ++rf) {
            int rl = rbase + rf * 16 + lr;
            if (rl > NN - 1) rl = NN - 1;
#pragma unroll
            for (int kk = 0; kk < 4; ++kk) {
                size_t off = (size_t)rl * HD + kk * 32 + lg * 8;
                if constexpr (F32A) {
                    const float* xp = (const float*)A1 + off;
                    float4 x0 = *reinterpret_cast<const float4*>(xp);
                    float4 x1 = *reinterpret_cast<const float4*>(xp + 4);
                    bf16x8 f;
                    f[0] = f2bf(x0.x); f[1] = f2bf(x0.y); f[2] = f2bf(x0.z); f[3] = f2bf(x0.w);
                    f[4] = f2bf(x1.x); f[5] = f2bf(x1.y); f[6] = f2bf(x1.z); f[7] = f2bf(x1.w);
                    a1[rf][kk] = f;
                } else {
                    a1[rf][kk] = *reinterpret_cast<const bf16x8*>((const short*)A1 + off);
                }
                if (DUAL) a2[rf][kk] = *reinterpret_cast<const bf16x8*>((const short*)A2 + off);
            }
        }
        f32x4 acc[2][2] = {};
#pragma unroll
        for (int kk = 0; kk < 4; ++kk)
#pragma unroll
            for (int cc = 0; cc < 2; ++cc)
#pragma unroll
                for (int rf = 0; rf < 2; ++rf) {
                    acc[rf][cc] = __builtin_amdgcn_mfma_f32_16x16x32_bf16(bf1[cc][kk], a1[rf][kk], acc[rf][cc], 0, 0, 0);
                    if (DUAL)
                        acc[rf][cc] = __builtin_amdgcn_mfma_f32_16x16x32_bf16(bf2[cc][kk], a2[rf][kk], acc[rf][cc], 0, 0, 0);
                }
        // store + stats: lane holds row = rbase+rf*16+lr, cols (wv*2+cc)*16 + lg*4 + 0..3
#pragma unroll
        for (int rf = 0; rf < 2; ++rf) {
            int row = rbase + rf * 16 + lr;
            if (row < NN) {
#pragma unroll
                for (int cc = 0; cc < 2; ++cc) {
                    f32x4 v = acc[rf][cc];
                    *reinterpret_cast<f32x4*>(&Y[(size_t)row * HD + (wv * 2 + cc) * 16 + lg * 4]) = v;
                    ss[cc] += v;
                    sq[cc] += v * v;
                }
            }
        }
    }

    // reduce stats over the 16 lanes sharing lg (different rows, same cols)
#pragma unroll
    for (int cc = 0; cc < 2; ++cc)
#pragma unroll
        for (int j = 0; j < 4; ++j) {
            float a = ss[cc][j], b = sq[cc][j];
#pragma unroll
            for (int m = 1; m < 16; m <<= 1) {
                a += __shfl_xor(a, m);
                b += __shfl_xor(b, m);
            }
            if (lr == 0) {
                int col = (wv * 2 + cc) * 16 + lg * 4 + j;
                atomicAdd(&stats[col], a);
                atomicAdd(&stats[HD + col], b);
            }
        }
}

// ---------------- BN fold + apply (writes bf16 h) ----------------
__global__ void bn_fold(const float* __restrict__ stats, const float* __restrict__ scale,
                        const float* __restrict__ bias, float* __restrict__ bnp) {
    int t = threadIdx.x;  // 128
    float mu = stats[t] * (1.0f / NN);
    float var = stats[HD + t] * (1.0f / NN) - mu * mu;
    float sc = scale[t] * rsqrtf(var + BN_EPS);
    bnp[t] = sc;
    bnp[HD + t] = bias[t] - mu * sc;
}

__global__ __launch_bounds__(256) void bn_relu(const float* __restrict__ Hp,
                                               const float* __restrict__ bnp,
                                               ushort* __restrict__ Hb) {
    int i = blockIdx.x * 256 + threadIdx.x;  // one thread per 8 features
    if (i >= NN * HD / 8) return;
    int mb = (i & 15) * 8;
    const float4* hp = reinterpret_cast<const float4*>(Hp) + (size_t)i * 2;
    float4 a = hp[0], b = hp[1];
    float4 sa = *reinterpret_cast<const float4*>(&bnp[mb]);
    float4 sb = *reinterpret_cast<const float4*>(&bnp[mb + 4]);
    float4 ba = *reinterpret_cast<const float4*>(&bnp[HD + mb]);
    float4 bb = *reinterpret_cast<const float4*>(&bnp[HD + mb + 4]);
    float v0 = fmaxf(a.x * sa.x + ba.x, 0.f);
    float v1 = fmaxf(a.y * sa.y + ba.y, 0.f);
    float v2 = fmaxf(a.z * sa.z + ba.z, 0.f);
    float v3 = fmaxf(a.w * sa.w + ba.w, 0.f);
    float v4 = fmaxf(b.x * sb.x + bb.x, 0.f);
    float v5 = fmaxf(b.y * sb.y + bb.y, 0.f);
    float v6 = fmaxf(b.z * sb.z + bb.z, 0.f);
    float v7 = fmaxf(b.w * sb.w + bb.w, 0.f);
    uint4 o;
    o.x = (unsigned)(unsigned short)f2bf(v0) | ((unsigned)(unsigned short)f2bf(v1) << 16);
    o.y = (unsigned)(unsigned short)f2bf(v2) | ((unsigned)(unsigned short)f2bf(v3) << 16);
    o.z = (unsigned)(unsigned short)f2bf(v4) | ((unsigned)(unsigned short)f2bf(v5) << 16);
    o.w = (unsigned)(unsigned short)f2bf(v6) | ((unsigned)(unsigned short)f2bf(v7) << 16);
    *reinterpret_cast<uint4*>(Hb + (size_t)i * 8) = o;
}

// ---------------- aggregation (bf16 in/out): agg[n] = invdeg[n]*sum h[adj] ----------------
__global__ __launch_bounds__(256) void agg_kernel(const ushort* __restrict__ H,
                                                  const int* __restrict__ adj,
                                                  const int* __restrict__ rowptr,
                                                  const float* __restrict__ invdeg,
                                                  ushort* __restrict__ A) {
    int node = blockIdx.x * 4 + (threadIdx.x >> 6);
    if (node >= NN) return;
    int lane = threadIdx.x & 63;
    int b = rowptr[node], e = rowptr[node + 1];
    float ax = 0.f, ay = 0.f;
    for (int i = b; i < e; ++i) {
        int s = adj[i];
        unsigned int v = *reinterpret_cast<const unsigned int*>(&H[(size_t)s * HD + lane * 2]);
        ax += bflo(v);
        ay += bfhi(v);
    }
    float id = invdeg[node];
    unsigned int lo = (unsigned short)f2bf(ax * id);
    unsigned int hi = (unsigned short)f2bf(ay * id);
    *reinterpret_cast<unsigned int*>(&A[(size_t)node * HD + lane * 2]) = lo | (hi << 16);
}

// ---------------- output GEMM (fp32 dot): out[n,c] = sum_k h[n,k]*W[c,k] + b[c] ----------------
__global__ __launch_bounds__(256) void out_gemm(const ushort* __restrict__ H,
                                                const float* __restrict__ W,
                                                const float* __restrict__ B,
                                                float* __restrict__ out) {
    __shared__ float wlds[NCLS * 132];
    __shared__ float xlds[6 * HD];
    int t = threadIdx.x;
    for (int j = t; j < NCLS * HD; j += 256) {
        int c = j >> 7, k = j & 127;
        wlds[c * 132 + k] = W[j];
    }
    __syncthreads();
    int r = t / NCLS, c = t % NCLS;
    bool act = t < 6 * NCLS;
    float bv = act ? B[c] : 0.f;
    const int NT = (NN + 5) / 6;
    for (int tile = blockIdx.x; tile < NT; tile += gridDim.x) {
        int r0 = tile * 6;
        __syncthreads();
        const unsigned int* hp = reinterpret_cast<const unsigned int*>(H + (size_t)r0 * HD);
        for (int j = t; j < 3 * HD; j += 256) {  // 384 uints = 768 bf16
            unsigned int v = hp[j];
            xlds[j * 2] = bflo(v);
            xlds[j * 2 + 1] = bfhi(v);
        }
        __syncthreads();
        if (!act) continue;
        int row = r0 + r;
        if (row < NN) {
            float acc = 0.f;
#pragma unroll
            for (int kk = 0; kk < HD; kk += 4) {
                float4 w = *reinterpret_cast<float4*>(&wlds[c * 132 + kk]);
                float4 xv = *reinterpret_cast<float4*>(&xlds[r * HD + kk]);
                acc += w.x * xv.x + w.y * xv.y + w.z * xv.z + w.w * xv.w;
            }
            out[(size_t)row * NCLS + c] = acc + bv;
        }
    }
}

extern "C" void kernel_launch(void* const* d_in, const int* in_sizes, int n_in,
                              void* d_out, int out_size, void* d_ws, size_t ws_size,
                              hipStream_t stream) {
    const float* x = (const float*)d_in[0];
    const void* ei = d_in[1];
    const float* fc0_w = (const float*)d_in[2];
    const float* bn_scale = (const float*)d_in[4];
    const float* bn_bias = (const float*)d_in[5];
    const float* lin_l = (const float*)d_in[6];
    const float* lin_r = (const float*)d_in[7];
    const float* W_w = (const float*)d_in[8];
    const float* out_w = (const float*)d_in[10];
    const float* out_b = (const float*)d_in[11];
    float* out = (float*)d_out;

    // ---- workspace carve-up (256B aligned) ----
    char* p = (char*)d_ws;
    auto alloc = [&](size_t bytes) -> void* {
        void* r = (void*)p;
        p += (bytes + 255) & ~(size_t)255;
        return r;
    };
    int* deg = (int*)alloc(NN * 4);
    int* cursor = (int*)alloc(NN * 4);
    float* stats = (float*)alloc(3 * 256 * 4);  // [3][sum128|sumsq128]
    int* eflag = (int*)alloc(256);
    size_t ctrl_bytes = (size_t)(p - (char*)d_ws);
    int* esrc = (int*)alloc(EE * 4);
    int* edst = (int*)alloc(EE * 4);
    int* rowptr = (int*)alloc((NN + 1) * 4);
    float* invdeg = (float*)alloc(NN * 4);
    int* adj = (int*)alloc(EE * 4);
    int* bsum = (int*)alloc(256 * 4);
    int* boff = (int*)alloc(256 * 4);
    float* bnp = (float*)alloc(3 * 256 * 4);       // [3][scale128|bias128]
    ushort* Wcb = (ushort*)alloc(4 * HD * HD * 2); // [layer][l/r][128][128] bf16
    ushort* wfc0 = (ushort*)alloc(HD * HD * 2);    // fc0_w bf16
    float* hpre = (float*)alloc((size_t)NN * HD * 4);
    ushort* hb = (ushort*)alloc((size_t)NN * HD * 2);
    ushort* aggb = (ushort*)alloc((size_t)NN * HD * 2);

    hipMemsetAsync(d_ws, 0, ctrl_bytes, stream);

    // edge decode + degree
    detect_kernel<<<1, 256, 0, stream>>>(ei, eflag);
    decode_deg_kernel<<<1250, 512, 0, stream>>>(ei, eflag, esrc, edst, deg);

    // parallel scan -> rowptr/invdeg, then CSR fill
    deg_blocksum<<<196, 256, 0, stream>>>(deg, bsum);
    scan_bsums<<<1, 256, 0, stream>>>(bsum, boff);
    rowptr_fill<<<196, 256, 0, stream>>>(deg, boff, rowptr, invdeg);
    fill_kernel<<<1250, 512, 0, stream>>>(esrc, edst, rowptr, cursor, adj);

    // weights: combined (bf16) + fc0 (bf16)
    combine_w<<<dim3(HD, 4), HD, 0, stream>>>(W_w, lin_l, lin_r, Wcb);
    convw_kernel<<<64, 256, 0, stream>>>(fc0_w, wfc0);

    // fc0 + BN0 + ReLU (fc0_b dropped: cancelled by BN)
    gemm_mfma<false, true><<<NT32, 256, 0, stream>>>(x, nullptr, wfc0, nullptr, hpre, stats);
    bn_fold<<<1, 128, 0, stream>>>(stats, bn_scale, bn_bias, bnp);
    bn_relu<<<3125, 256, 0, stream>>>(hpre, bnp, hb);

    for (int layer = 0; layer < 2; ++layer) {
        agg_kernel<<<(NN + 3) / 4, 256, 0, stream>>>(hb, adj, rowptr, invdeg, aggb);
        const ushort* Wl = Wcb + (size_t)(layer * 2 + 0) * HD * HD;
        const ushort* Wr = Wcb + (size_t)(layer * 2 + 1) * HD * HD;
        float* st = stats + (layer + 1) * 256;
        // fused: hpre = aggb@Wl^T + hb@Wr^T, stats fused (W_b dropped: cancelled by BN)
        gemm_mfma<true, false><<<NT32, 256, 0, stream>>>(aggb, hb, Wl, Wr, hpre, st);
        float* bp = bnp + (layer + 1) * 256;
        bn_fold<<<1, 128, 0, stream>>>(st, bn_scale + (layer + 1) * HD, bn_bias + (layer + 1) * HD, bp);
        bn_relu<<<3125, 256, 0, stream>>>(hpre, bp, hb);
    }

    out_gemm<<<512, 256, 0, stream>>>(hb, out_w, out_b, out);
}

// Round 6
// 545.556 us; speedup vs baseline: 1.4271x; 1.4271x over previous
//
#include <hip/hip_runtime.h>
#include <hip/hip_bf16.h>

#define NN 50000
#define EE 640000
#define HD 128
#define NCLS 40
#define BN_EPS 1e-5f
#define NT64 782  // ceil(NN/64)

typedef short bf16x8 __attribute__((ext_vector_type(8)));
typedef float f32x4 __attribute__((ext_vector_type(4)));

__device__ __forceinline__ short f2bf(float f) {
    __hip_bfloat16 h = __float2bfloat16(f);
    return *reinterpret_cast<short*>(&h);
}
__device__ __forceinline__ float bflo(unsigned int v) { return __uint_as_float(v << 16); }
__device__ __forceinline__ float bfhi(unsigned int v) { return __uint_as_float(v & 0xffff0000u); }
__device__ __forceinline__ unsigned int packbf(float a, float b) {
    return (unsigned)(unsigned short)f2bf(a) | ((unsigned)(unsigned short)f2bf(b) << 16);
}

// ---------------- edge_index width detect + decode (+degree count) ----------------
__global__ void detect_kernel(const void* __restrict__ ei, int* __restrict__ flag) {
    int t = threadIdx.x;  // 256
    const long long* p = (const long long*)ei;
    long long v = p[(size_t)t * (EE / 256)];
    if (v < 0 || v >= NN) atomicOr(flag, 1);  // flag=1 -> int32 data
}

__global__ void decode_deg_kernel(const void* __restrict__ ei, const int* __restrict__ flag,
                                  int* __restrict__ src, int* __restrict__ dst,
                                  int* __restrict__ deg) {
    bool narrow = (*flag != 0);
    for (int e = blockIdx.x * blockDim.x + threadIdx.x; e < EE; e += gridDim.x * blockDim.x) {
        int s, d;
        if (narrow) {
            const int* p = (const int*)ei;
            s = p[e]; d = p[EE + e];
        } else {
            const long long* p = (const long long*)ei;
            s = (int)p[e]; d = (int)p[EE + e];
        }
        src[e] = s;
        dst[e] = d;
        atomicAdd(&deg[d], 1);
    }
}

// ---------------- parallel scan: deg -> rowptr, invdeg ----------------
__global__ void deg_blocksum(const int* __restrict__ deg, int* __restrict__ bsum) {
    int i = blockIdx.x * 256 + threadIdx.x;
    int d = (i < NN) ? deg[i] : 0;
#pragma unroll
    for (int o = 32; o; o >>= 1) d += __shfl_down(d, o);
    __shared__ int ws[4];
    if ((threadIdx.x & 63) == 0) ws[threadIdx.x >> 6] = d;
    __syncthreads();
    if (threadIdx.x == 0) bsum[blockIdx.x] = ws[0] + ws[1] + ws[2] + ws[3];
}

__global__ void scan_bsums(const int* __restrict__ bsum, int* __restrict__ boff) {
    __shared__ int s[256];
    int t = threadIdx.x;
    int v = (t < 196) ? bsum[t] : 0;
    s[t] = v;
    __syncthreads();
    for (int o = 1; o < 256; o <<= 1) {
        int u = (t >= o) ? s[t - o] : 0;
        __syncthreads();
        s[t] += u;
        __syncthreads();
    }
    if (t < 196) boff[t] = s[t] - v;  // exclusive
}

__global__ void rowptr_fill(const int* __restrict__ deg, const int* __restrict__ boff,
                            int* __restrict__ rowptr, float* __restrict__ invdeg) {
    int b = blockIdx.x, t = threadIdx.x, i = b * 256 + t;
    int d = (i < NN) ? deg[i] : 0;
    __shared__ int s[256];
    s[t] = d;
    __syncthreads();
    for (int o = 1; o < 256; o <<= 1) {
        int u = (t >= o) ? s[t - o] : 0;
        __syncthreads();
        s[t] += u;
        __syncthreads();
    }
    int excl = s[t] - d + boff[b];
    if (i < NN) {
        rowptr[i] = excl;
        invdeg[i] = 1.0f / (float)(d > 1 ? d : 1);
        if (i == NN - 1) rowptr[NN] = excl + d;
    }
}

__global__ void fill_kernel(const int* __restrict__ src, const int* __restrict__ dst,
                            const int* __restrict__ rowptr, int* __restrict__ cursor,
                            int* __restrict__ adj) {
    for (int e = blockIdx.x * blockDim.x + threadIdx.x; e < EE; e += gridDim.x * blockDim.x) {
        int d = dst[e];
        int pos = atomicAdd(&cursor[d], 1);
        adj[rowptr[d] + pos] = src[e];
    }
}

// ---------------- weights: Wc[which] = bf16(W_w @ lin_{l/r}[layer]); fc0 -> bf16 ----------------
__global__ void combine_w(const float* __restrict__ Ww, const float* __restrict__ linl,
                          const float* __restrict__ linr, ushort* __restrict__ Wcb) {
    int k = threadIdx.x;
    int m = blockIdx.x;
    int which = blockIdx.y;  // layer = which>>1, l/r = which&1
    const float* lin = ((which & 1) ? linr : linl) + (which >> 1) * HD * HD;
    __shared__ float wrow[HD];
    wrow[k] = Ww[m * HD + k];
    __syncthreads();
    float acc = 0.f;
    for (int j = 0; j < HD; ++j) acc += wrow[j] * lin[j * HD + k];
    Wcb[which * HD * HD + m * HD + k] = (unsigned short)f2bf(acc);
}

__global__ void convw_kernel(const float* __restrict__ W, ushort* __restrict__ Wb) {
    int i = blockIdx.x * 256 + threadIdx.x;
    if (i < HD * HD) Wb[i] = (unsigned short)f2bf(W[i]);
}

// x (fp32) -> bf16, 8 elems/thread
__global__ __launch_bounds__(256) void convx_kernel(const float* __restrict__ X,
                                                    ushort* __restrict__ Xb) {
    int i = blockIdx.x * 256 + threadIdx.x;
    if (i >= NN * HD / 8) return;
    const float4* xp = reinterpret_cast<const float4*>(X) + (size_t)i * 2;
    float4 a = xp[0], b = xp[1];
    uint4 o;
    o.x = packbf(a.x, a.y);
    o.y = packbf(a.z, a.w);
    o.z = packbf(b.x, b.y);
    o.w = packbf(b.z, b.w);
    *reinterpret_cast<uint4*>(Xb + (size_t)i * 8) = o;
}

// ---------------- MFMA GEMM: LDS-staged A, reg weights, one 64-row tile per block --------
// Y[n,m] = sum_k A1[n,k]*W1[m,k] (+ A2[n,k]*W2[m,k]); per-column stats fused; no bias
// (BatchNorm cancels additive per-column constants). Wave wv owns cols [wv*32, wv*32+32).
// LDS tiles XOR-swizzled: lds[row][c ^ ((row&15)<<4)] = A[row][c]  (bytes), breaking the
// 16-way bank conflict of stride-256B column reads down to 4-way.
template <bool DUAL>
__global__ __launch_bounds__(256) void gemm_mfma(const ushort* __restrict__ A1g,
                                                 const ushort* __restrict__ A2g,
                                                 const ushort* __restrict__ W1,
                                                 const ushort* __restrict__ W2,
                                                 float* __restrict__ Y,
                                                 float* __restrict__ stats) {
    __shared__ __align__(16) char lds[DUAL ? 32768 : 16384];
    int t = threadIdx.x;
    int l = t & 63, wv = t >> 6;
    int lr = l & 15, lg = l >> 4;
    int rbase = blockIdx.x * 64;

    // ---- issue all staging loads upfront (independent, one latency window) ----
    bf16x8 st1[4], st2[4];
    int osw[4];
#pragma unroll
    for (int i = 0; i < 4; ++i) {
        int o = i * 4096 + t * 16;  // linear dest offset in tile region
        int row = o >> 8, c = o & 255;
        osw[i] = row * 256 + (c ^ ((row & 15) << 4));
        int grow = rbase + row;
        if (grow > NN - 1) grow = NN - 1;
        st1[i] = *reinterpret_cast<const bf16x8*>((const char*)A1g + (size_t)grow * 256 + c);
        if constexpr (DUAL)
            st2[i] = *reinterpret_cast<const bf16x8*>((const char*)A2g + (size_t)grow * 256 + c);
    }

    // ---- weight fragments (bf16), wave's 32-col slice (L2-hot across blocks) ----
    bf16x8 bf1[2][4], bf2[2][4];
#pragma unroll
    for (int cc = 0; cc < 2; ++cc)
#pragma unroll
        for (int kk = 0; kk < 4; ++kk) {
            int wrow = (wv * 2 + cc) * 16 + lr;
            bf1[cc][kk] = *reinterpret_cast<const bf16x8*>(W1 + (size_t)wrow * HD + kk * 32 + lg * 8);
            if constexpr (DUAL)
                bf2[cc][kk] = *reinterpret_cast<const bf16x8*>(W2 + (size_t)wrow * HD + kk * 32 + lg * 8);
        }

    // ---- swizzled ds_write ----
#pragma unroll
    for (int i = 0; i < 4; ++i) {
        *reinterpret_cast<bf16x8*>(&lds[osw[i]]) = st1[i];
        if constexpr (DUAL) *reinterpret_cast<bf16x8*>(&lds[16384 + osw[i]]) = st2[i];
    }
    __syncthreads();

    // ---- compute ----
    f32x4 acc[4][2] = {};
#pragma unroll
    for (int rf = 0; rf < 4; ++rf) {
        int row = rf * 16 + lr;
        int swz = (row & 15) << 4;
        bf16x8 a1[4], a2[4];
#pragma unroll
        for (int kk = 0; kk < 4; ++kk) {
            int s = row * 256 + ((kk * 64 + lg * 16) ^ swz);
            a1[kk] = *reinterpret_cast<const bf16x8*>(&lds[s]);
            if constexpr (DUAL) a2[kk] = *reinterpret_cast<const bf16x8*>(&lds[16384 + s]);
        }
#pragma unroll
        for (int kk = 0; kk < 4; ++kk)
#pragma unroll
            for (int cc = 0; cc < 2; ++cc) {
                acc[rf][cc] = __builtin_amdgcn_mfma_f32_16x16x32_bf16(bf1[cc][kk], a1[kk], acc[rf][cc], 0, 0, 0);
                if constexpr (DUAL)
                    acc[rf][cc] = __builtin_amdgcn_mfma_f32_16x16x32_bf16(bf2[cc][kk], a2[kk], acc[rf][cc], 0, 0, 0);
            }
    }

    // ---- store + stats: lane row = rbase+rf*16+lr, cols (wv*2+cc)*16 + lg*4 + 0..3 ----
    f32x4 ss[2] = {}, sq[2] = {};
#pragma unroll
    for (int rf = 0; rf < 4; ++rf) {
        int row = rbase + rf * 16 + lr;
        if (row < NN) {
#pragma unroll
            for (int cc = 0; cc < 2; ++cc) {
                f32x4 v = acc[rf][cc];
                *reinterpret_cast<f32x4*>(&Y[(size_t)row * HD + (wv * 2 + cc) * 16 + lg * 4]) = v;
                ss[cc] += v;
                sq[cc] += v * v;
            }
        }
    }

    // reduce stats over the 16 lanes lr (different rows, same cols)
#pragma unroll
    for (int cc = 0; cc < 2; ++cc)
#pragma unroll
        for (int j = 0; j < 4; ++j) {
            float a = ss[cc][j], b = sq[cc][j];
#pragma unroll
            for (int m = 1; m < 16; m <<= 1) {
                a += __shfl_xor(a, m);
                b += __shfl_xor(b, m);
            }
            if (lr == 0) {
                int col = (wv * 2 + cc) * 16 + lg * 4 + j;
                atomicAdd(&stats[col], a);
                atomicAdd(&stats[HD + col], b);
            }
        }
}

// ---------------- BN fold + apply (writes bf16 h) ----------------
__global__ void bn_fold(const float* __restrict__ stats, const float* __restrict__ scale,
                        const float* __restrict__ bias, float* __restrict__ bnp) {
    int t = threadIdx.x;  // 128
    float mu = stats[t] * (1.0f / NN);
    float var = stats[HD + t] * (1.0f / NN) - mu * mu;
    float sc = scale[t] * rsqrtf(var + BN_EPS);
    bnp[t] = sc;
    bnp[HD + t] = bias[t] - mu * sc;
}

__global__ __launch_bounds__(256) void bn_relu(const float* __restrict__ Hp,
                                               const float* __restrict__ bnp,
                                               ushort* __restrict__ Hb) {
    int i = blockIdx.x * 256 + threadIdx.x;  // one thread per 8 features
    if (i >= NN * HD / 8) return;
    int mb = (i & 15) * 8;
    const float4* hp = reinterpret_cast<const float4*>(Hp) + (size_t)i * 2;
    float4 a = hp[0], b = hp[1];
    float4 sa = *reinterpret_cast<const float4*>(&bnp[mb]);
    float4 sb = *reinterpret_cast<const float4*>(&bnp[mb + 4]);
    float4 ba = *reinterpret_cast<const float4*>(&bnp[HD + mb]);
    float4 bb = *reinterpret_cast<const float4*>(&bnp[HD + mb + 4]);
    float v0 = fmaxf(a.x * sa.x + ba.x, 0.f);
    float v1 = fmaxf(a.y * sa.y + ba.y, 0.f);
    float v2 = fmaxf(a.z * sa.z + ba.z, 0.f);
    float v3 = fmaxf(a.w * sa.w + ba.w, 0.f);
    float v4 = fmaxf(b.x * sb.x + bb.x, 0.f);
    float v5 = fmaxf(b.y * sb.y + bb.y, 0.f);
    float v6 = fmaxf(b.z * sb.z + bb.z, 0.f);
    float v7 = fmaxf(b.w * sb.w + bb.w, 0.f);
    uint4 o;
    o.x = packbf(v0, v1);
    o.y = packbf(v2, v3);
    o.z = packbf(v4, v5);
    o.w = packbf(v6, v7);
    *reinterpret_cast<uint4*>(Hb + (size_t)i * 8) = o;
}

// ---------------- aggregation (bf16 in/out): agg[n] = invdeg[n]*sum h[adj] ----------------
__global__ __launch_bounds__(256) void agg_kernel(const ushort* __restrict__ H,
                                                  const int* __restrict__ adj,
                                                  const int* __restrict__ rowptr,
                                                  const float* __restrict__ invdeg,
                                                  ushort* __restrict__ A) {
    int node = blockIdx.x * 4 + (threadIdx.x >> 6);
    if (node >= NN) return;
    int lane = threadIdx.x & 63;
    int b = rowptr[node], e = rowptr[node + 1];
    float ax = 0.f, ay = 0.f;
    for (int i = b; i < e; ++i) {
        int s = adj[i];
        unsigned int v = *reinterpret_cast<const unsigned int*>(&H[(size_t)s * HD + lane * 2]);
        ax += bflo(v);
        ay += bfhi(v);
    }
    float id = invdeg[node];
    *reinterpret_cast<unsigned int*>(&A[(size_t)node * HD + lane * 2]) = packbf(ax * id, ay * id);
}

// ---------------- output GEMM (fp32 dot): out[n,c] = sum_k h[n,k]*W[c,k] + b[c] ----------------
__global__ __launch_bounds__(256) void out_gemm(const ushort* __restrict__ H,
                                                const float* __restrict__ W,
                                                const float* __restrict__ B,
                                                float* __restrict__ out) {
    __shared__ float wlds[NCLS * 132];
    __shared__ float xlds[6 * HD];
    int t = threadIdx.x;
    for (int j = t; j < NCLS * HD; j += 256) {
        int c = j >> 7, k = j & 127;
        wlds[c * 132 + k] = W[j];
    }
    __syncthreads();
    int r = t / NCLS, c = t % NCLS;
    bool act = t < 6 * NCLS;
    float bv = act ? B[c] : 0.f;
    const int NT = (NN + 5) / 6;
    for (int tile = blockIdx.x; tile < NT; tile += gridDim.x) {
        int r0 = tile * 6;
        __syncthreads();
        const unsigned int* hp = reinterpret_cast<const unsigned int*>(H + (size_t)r0 * HD);
        for (int j = t; j < 3 * HD; j += 256) {  // 384 uints = 768 bf16
            unsigned int v = hp[j];
            xlds[j * 2] = bflo(v);
            xlds[j * 2 + 1] = bfhi(v);
        }
        __syncthreads();
        if (!act) continue;
        int row = r0 + r;
        if (row < NN) {
            float acc = 0.f;
#pragma unroll
            for (int kk = 0; kk < HD; kk += 4) {
                float4 w = *reinterpret_cast<float4*>(&wlds[c * 132 + kk]);
                float4 xv = *reinterpret_cast<float4*>(&xlds[r * HD + kk]);
                acc += w.x * xv.x + w.y * xv.y + w.z * xv.z + w.w * xv.w;
            }
            out[(size_t)row * NCLS + c] = acc + bv;
        }
    }
}

extern "C" void kernel_launch(void* const* d_in, const int* in_sizes, int n_in,
                              void* d_out, int out_size, void* d_ws, size_t ws_size,
                              hipStream_t stream) {
    const float* x = (const float*)d_in[0];
    const void* ei = d_in[1];
    const float* fc0_w = (const float*)d_in[2];
    const float* bn_scale = (const float*)d_in[4];
    const float* bn_bias = (const float*)d_in[5];
    const float* lin_l = (const float*)d_in[6];
    const float* lin_r = (const float*)d_in[7];
    const float* W_w = (const float*)d_in[8];
    const float* out_w = (const float*)d_in[10];
    const float* out_b = (const float*)d_in[11];
    float* out = (float*)d_out;

    // ---- workspace carve-up (256B aligned) ----
    char* p = (char*)d_ws;
    auto alloc = [&](size_t bytes) -> void* {
        void* r = (void*)p;
        p += (bytes + 255) & ~(size_t)255;
        return r;
    };
    int* deg = (int*)alloc(NN * 4);
    int* cursor = (int*)alloc(NN * 4);
    float* stats = (float*)alloc(3 * 256 * 4);  // [3][sum128|sumsq128]
    int* eflag = (int*)alloc(256);
    size_t ctrl_bytes = (size_t)(p - (char*)d_ws);
    int* esrc = (int*)alloc(EE * 4);
    int* edst = (int*)alloc(EE * 4);
    int* rowptr = (int*)alloc((NN + 1) * 4);
    float* invdeg = (float*)alloc(NN * 4);
    int* adj = (int*)alloc(EE * 4);
    int* bsum = (int*)alloc(256 * 4);
    int* boff = (int*)alloc(256 * 4);
    float* bnp = (float*)alloc(3 * 256 * 4);        // [3][scale128|bias128]
    ushort* Wcb = (ushort*)alloc(4 * HD * HD * 2);  // [layer][l/r][128][128] bf16
    ushort* wfc0 = (ushort*)alloc(HD * HD * 2);     // fc0_w bf16
    float* hpre = (float*)alloc((size_t)NN * HD * 4);
    ushort* hb = (ushort*)alloc((size_t)NN * HD * 2);
    ushort* aggb = (ushort*)alloc((size_t)NN * HD * 2);  // also reused as bf16 x

    hipMemsetAsync(d_ws, 0, ctrl_bytes, stream);

    // edge decode + degree
    detect_kernel<<<1, 256, 0, stream>>>(ei, eflag);
    decode_deg_kernel<<<1250, 512, 0, stream>>>(ei, eflag, esrc, edst, deg);

    // parallel scan -> rowptr/invdeg, then CSR fill
    deg_blocksum<<<196, 256, 0, stream>>>(deg, bsum);
    scan_bsums<<<1, 256, 0, stream>>>(bsum, boff);
    rowptr_fill<<<196, 256, 0, stream>>>(deg, boff, rowptr, invdeg);
    fill_kernel<<<1250, 512, 0, stream>>>(esrc, edst, rowptr, cursor, adj);

    // weights: combined (bf16) + fc0 (bf16); x -> bf16 (into aggb, free until layer0 agg)
    combine_w<<<dim3(HD, 4), HD, 0, stream>>>(W_w, lin_l, lin_r, Wcb);
    convw_kernel<<<64, 256, 0, stream>>>(fc0_w, wfc0);
    convx_kernel<<<3125, 256, 0, stream>>>(x, (ushort*)aggb);

    // fc0 + BN0 + ReLU (fc0_b dropped: cancelled by BN)
    gemm_mfma<false><<<NT64, 256, 0, stream>>>((const ushort*)aggb, nullptr, wfc0, nullptr, hpre, stats);
    bn_fold<<<1, 128, 0, stream>>>(stats, bn_scale, bn_bias, bnp);
    bn_relu<<<3125, 256, 0, stream>>>(hpre, bnp, hb);

    for (int layer = 0; layer < 2; ++layer) {
        agg_kernel<<<(NN + 3) / 4, 256, 0, stream>>>(hb, adj, rowptr, invdeg, aggb);
        const ushort* Wl = Wcb + (size_t)(layer * 2 + 0) * HD * HD;
        const ushort* Wr = Wcb + (size_t)(layer * 2 + 1) * HD * HD;
        float* st = stats + (layer + 1) * 256;
        // fused: hpre = aggb@Wl^T + hb@Wr^T, stats fused (W_b dropped: cancelled by BN)
        gemm_mfma<true><<<NT64, 256, 0, stream>>>(aggb, hb, Wl, Wr, hpre, st);
        float* bp = bnp + (layer + 1) * 256;
        bn_fold<<<1, 128, 0, stream>>>(st, bn_scale + (layer + 1) * HD, bn_bias + (layer + 1) * HD, bp);
        bn_relu<<<3125, 256, 0, stream>>>(hpre, bp, hb);
    }

    out_gemm<<<512, 256, 0, stream>>>(hb, out_w, out_b, out);
}

// Round 7
// 500.233 us; speedup vs baseline: 1.5564x; 1.0906x over previous
//
#include <hip/hip_runtime.h>
#include <hip/hip_bf16.h>

#define NN 50000
#define EE 640000
#define HD 128
#define NCLS 40
#define BN_EPS 1e-5f
#define NTT 3125   // NN / 16 exactly
#define GGRID 512  // gemm grid

typedef short bf16x8 __attribute__((ext_vector_type(8)));
typedef float f32x4 __attribute__((ext_vector_type(4)));

__device__ __forceinline__ short f2bf(float f) {
    __hip_bfloat16 h = __float2bfloat16(f);
    return *reinterpret_cast<short*>(&h);
}
__device__ __forceinline__ float bflo(unsigned int v) { return __uint_as_float(v << 16); }
__device__ __forceinline__ float bfhi(unsigned int v) { return __uint_as_float(v & 0xffff0000u); }
__device__ __forceinline__ unsigned int packbf(float a, float b) {
    return (unsigned)(unsigned short)f2bf(a) | ((unsigned)(unsigned short)f2bf(b) << 16);
}

// ---------------- edge_index width detect + decode (+degree count) ----------------
__global__ void detect_kernel(const void* __restrict__ ei, int* __restrict__ flag) {
    int t = threadIdx.x;  // 256
    const long long* p = (const long long*)ei;
    long long v = p[(size_t)t * (EE / 256)];
    if (v < 0 || v >= NN) atomicOr(flag, 1);  // flag=1 -> int32 data
}

__global__ void decode_deg_kernel(const void* __restrict__ ei, const int* __restrict__ flag,
                                  int* __restrict__ src, int* __restrict__ dst,
                                  int* __restrict__ deg) {
    bool narrow = (*flag != 0);
    for (int e = blockIdx.x * blockDim.x + threadIdx.x; e < EE; e += gridDim.x * blockDim.x) {
        int s, d;
        if (narrow) {
            const int* p = (const int*)ei;
            s = p[e]; d = p[EE + e];
        } else {
            const long long* p = (const long long*)ei;
            s = (int)p[e]; d = (int)p[EE + e];
        }
        src[e] = s;
        dst[e] = d;
        atomicAdd(&deg[d], 1);
    }
}

// ---------------- parallel scan: deg -> rowptr, invdeg ----------------
__global__ void deg_blocksum(const int* __restrict__ deg, int* __restrict__ bsum) {
    int i = blockIdx.x * 256 + threadIdx.x;
    int d = (i < NN) ? deg[i] : 0;
#pragma unroll
    for (int o = 32; o; o >>= 1) d += __shfl_down(d, o);
    __shared__ int ws[4];
    if ((threadIdx.x & 63) == 0) ws[threadIdx.x >> 6] = d;
    __syncthreads();
    if (threadIdx.x == 0) bsum[blockIdx.x] = ws[0] + ws[1] + ws[2] + ws[3];
}

__global__ void scan_bsums(const int* __restrict__ bsum, int* __restrict__ boff) {
    __shared__ int s[256];
    int t = threadIdx.x;
    int v = (t < 196) ? bsum[t] : 0;
    s[t] = v;
    __syncthreads();
    for (int o = 1; o < 256; o <<= 1) {
        int u = (t >= o) ? s[t - o] : 0;
        __syncthreads();
        s[t] += u;
        __syncthreads();
    }
    if (t < 196) boff[t] = s[t] - v;  // exclusive
}

__global__ void rowptr_fill(const int* __restrict__ deg, const int* __restrict__ boff,
                            int* __restrict__ rowptr, float* __restrict__ invdeg) {
    int b = blockIdx.x, t = threadIdx.x, i = b * 256 + t;
    int d = (i < NN) ? deg[i] : 0;
    __shared__ int s[256];
    s[t] = d;
    __syncthreads();
    for (int o = 1; o < 256; o <<= 1) {
        int u = (t >= o) ? s[t - o] : 0;
        __syncthreads();
        s[t] += u;
        __syncthreads();
    }
    int excl = s[t] - d + boff[b];
    if (i < NN) {
        rowptr[i] = excl;
        invdeg[i] = 1.0f / (float)(d > 1 ? d : 1);
        if (i == NN - 1) rowptr[NN] = excl + d;
    }
}

__global__ void fill_kernel(const int* __restrict__ src, const int* __restrict__ dst,
                            const int* __restrict__ rowptr, int* __restrict__ cursor,
                            int* __restrict__ adj) {
    for (int e = blockIdx.x * blockDim.x + threadIdx.x; e < EE; e += gridDim.x * blockDim.x) {
        int d = dst[e];
        int pos = atomicAdd(&cursor[d], 1);
        adj[rowptr[d] + pos] = src[e];
    }
}

// ---------------- weights: Wc[which] = bf16(W_w @ lin_{l/r}[layer]); fc0 -> bf16 ----------------
__global__ void combine_w(const float* __restrict__ Ww, const float* __restrict__ linl,
                          const float* __restrict__ linr, ushort* __restrict__ Wcb) {
    int k = threadIdx.x;
    int m = blockIdx.x;
    int which = blockIdx.y;  // layer = which>>1, l/r = which&1
    const float* lin = ((which & 1) ? linr : linl) + (which >> 1) * HD * HD;
    __shared__ float wrow[HD];
    wrow[k] = Ww[m * HD + k];
    __syncthreads();
    float acc = 0.f;
    for (int j = 0; j < HD; ++j) acc += wrow[j] * lin[j * HD + k];
    Wcb[which * HD * HD + m * HD + k] = (unsigned short)f2bf(acc);
}

__global__ void convw_kernel(const float* __restrict__ W, ushort* __restrict__ Wb) {
    int i = blockIdx.x * 256 + threadIdx.x;
    if (i < HD * HD) Wb[i] = (unsigned short)f2bf(W[i]);
}

// x (fp32) -> bf16, 8 elems/thread
__global__ __launch_bounds__(256) void convx_kernel(const float* __restrict__ X,
                                                    ushort* __restrict__ Xb) {
    int i = blockIdx.x * 256 + threadIdx.x;
    if (i >= NN * HD / 8) return;
    const float4* xp = reinterpret_cast<const float4*>(X) + (size_t)i * 2;
    float4 a = xp[0], b = xp[1];
    uint4 o;
    o.x = packbf(a.x, a.y);
    o.y = packbf(a.z, a.w);
    o.z = packbf(b.x, b.y);
    o.w = packbf(b.z, b.w);
    *reinterpret_cast<uint4*>(Xb + (size_t)i * 8) = o;
}

// ---------------- MFMA GEMM v3: persistent, register-resident, pipelined ----------------
// Y[n,m] = bf16( sum_k A1[n,k]*W1[m,k] (+ A2[n,k]*W2[m,k]) ); per-column stats fused
// from the fp32 accumulator (pre-rounding). No bias (BN cancels per-column constants).
// Block = 512 threads = 8 waves; wave w owns cols [w*16, w*16+16). Tile = 16 rows.
// NN = 16*3125 exactly -> no guards. 1-deep prefetch: loads for tile t+GGRID are in
// flight during tile t's MFMAs. Reg budget ~125 VGPR -> 4 waves/SIMD.
template <bool DUAL>
__device__ __forceinline__ void load_tile(const ushort* __restrict__ A1g,
                                          const ushort* __restrict__ A2g,
                                          int t, int lr, int lg,
                                          bf16x8* a1, bf16x8* a2) {
    size_t base = (size_t)(t * 16 + lr) * HD + lg * 8;
#pragma unroll
    for (int kk = 0; kk < 4; ++kk) {
        a1[kk] = *reinterpret_cast<const bf16x8*>(A1g + base + kk * 32);
        if constexpr (DUAL) a2[kk] = *reinterpret_cast<const bf16x8*>(A2g + base + kk * 32);
    }
}

template <bool DUAL>
__device__ __forceinline__ void comp_store(const bf16x8 (&bf1)[4], const bf16x8 (&bf2)[4],
                                           const bf16x8* a1, const bf16x8* a2,
                                           int t, int lr, int lg, int w,
                                           ushort* __restrict__ Y, f32x4& ss, f32x4& sq) {
    f32x4 acc = {};
#pragma unroll
    for (int kk = 0; kk < 4; ++kk) {
        acc = __builtin_amdgcn_mfma_f32_16x16x32_bf16(bf1[kk], a1[kk], acc, 0, 0, 0);
        if constexpr (DUAL)
            acc = __builtin_amdgcn_mfma_f32_16x16x32_bf16(bf2[kk], a2[kk], acc, 0, 0, 0);
    }
    int row = t * 16 + lr;
    uint2 o;
    o.x = packbf(acc[0], acc[1]);
    o.y = packbf(acc[2], acc[3]);
    *reinterpret_cast<uint2*>(Y + (size_t)row * HD + w * 16 + lg * 4) = o;
    ss += acc;
    sq += acc * acc;
}

template <bool DUAL>
__global__ __launch_bounds__(512, 3) void gemm_mfma(const ushort* __restrict__ A1g,
                                                    const ushort* __restrict__ A2g,
                                                    const ushort* __restrict__ W1,
                                                    const ushort* __restrict__ W2,
                                                    ushort* __restrict__ Y,
                                                    float* __restrict__ stats) {
    int tt = threadIdx.x;
    int l = tt & 63, w = tt >> 6;
    int lr = l & 15, lg = l >> 4;

    // weight fragments for this wave's 16-col slice (stay in regs for whole kernel)
    bf16x8 bf1[4], bf2[4];
#pragma unroll
    for (int kk = 0; kk < 4; ++kk) {
        size_t wb = (size_t)(w * 16 + lr) * HD + kk * 32 + lg * 8;
        bf1[kk] = *reinterpret_cast<const bf16x8*>(W1 + wb);
        if constexpr (DUAL) bf2[kk] = *reinterpret_cast<const bf16x8*>(W2 + wb);
    }

    f32x4 ss = {}, sq = {};
    bf16x8 pA1[4], pA2[4], pB1[4], pB2[4];

    int t = blockIdx.x;
    load_tile<DUAL>(A1g, A2g, t, lr, lg, pA1, pA2);
    for (;;) {
        int t1 = t + GGRID;
        if (t1 < NTT) load_tile<DUAL>(A1g, A2g, t1, lr, lg, pB1, pB2);
        comp_store<DUAL>(bf1, bf2, pA1, pA2, t, lr, lg, w, Y, ss, sq);
        if (t1 >= NTT) break;
        int t2 = t1 + GGRID;
        if (t2 < NTT) load_tile<DUAL>(A1g, A2g, t2, lr, lg, pA1, pA2);
        comp_store<DUAL>(bf1, bf2, pB1, pB2, t1, lr, lg, w, Y, ss, sq);
        if (t2 >= NTT) break;
        t = t2;
    }

    // stats: reduce across the 16 lr lanes (rows), then one atomic per col from lr==0
#pragma unroll
    for (int j = 0; j < 4; ++j) {
        float a = ss[j], b = sq[j];
#pragma unroll
        for (int m = 1; m < 16; m <<= 1) {
            a += __shfl_xor(a, m);
            b += __shfl_xor(b, m);
        }
        if (lr == 0) {
            int col = w * 16 + lg * 4 + j;
            atomicAdd(&stats[col], a);
            atomicAdd(&stats[HD + col], b);
        }
    }
}

// ---------------- BN fold + apply (bf16 in, bf16 out) ----------------
__global__ void bn_fold(const float* __restrict__ stats, const float* __restrict__ scale,
                        const float* __restrict__ bias, float* __restrict__ bnp) {
    int t = threadIdx.x;  // 128
    float mu = stats[t] * (1.0f / NN);
    float var = stats[HD + t] * (1.0f / NN) - mu * mu;
    float sc = scale[t] * rsqrtf(var + BN_EPS);
    bnp[t] = sc;
    bnp[HD + t] = bias[t] - mu * sc;
}

__global__ __launch_bounds__(256) void bn_relu(const ushort* __restrict__ Hp,
                                               const float* __restrict__ bnp,
                                               ushort* __restrict__ Hb) {
    int i = blockIdx.x * 256 + threadIdx.x;  // one thread per 8 features
    if (i >= NN * HD / 8) return;
    int mb = (i & 15) * 8;
    uint4 v = reinterpret_cast<const uint4*>(Hp)[i];
    float4 sa = *reinterpret_cast<const float4*>(&bnp[mb]);
    float4 sb = *reinterpret_cast<const float4*>(&bnp[mb + 4]);
    float4 ba = *reinterpret_cast<const float4*>(&bnp[HD + mb]);
    float4 bb = *reinterpret_cast<const float4*>(&bnp[HD + mb + 4]);
    float v0 = fmaxf(bflo(v.x) * sa.x + ba.x, 0.f);
    float v1 = fmaxf(bfhi(v.x) * sa.y + ba.y, 0.f);
    float v2 = fmaxf(bflo(v.y) * sa.z + ba.z, 0.f);
    float v3 = fmaxf(bfhi(v.y) * sa.w + ba.w, 0.f);
    float v4 = fmaxf(bflo(v.z) * sb.x + bb.x, 0.f);
    float v5 = fmaxf(bfhi(v.z) * sb.y + bb.y, 0.f);
    float v6 = fmaxf(bflo(v.w) * sb.z + bb.z, 0.f);
    float v7 = fmaxf(bfhi(v.w) * sb.w + bb.w, 0.f);
    uint4 o;
    o.x = packbf(v0, v1);
    o.y = packbf(v2, v3);
    o.z = packbf(v4, v5);
    o.w = packbf(v6, v7);
    *reinterpret_cast<uint4*>(Hb + (size_t)i * 8) = o;
}

// ---------------- aggregation (bf16 in/out): agg[n] = invdeg[n]*sum h[adj] ----------------
__global__ __launch_bounds__(256) void agg_kernel(const ushort* __restrict__ H,
                                                  const int* __restrict__ adj,
                                                  const int* __restrict__ rowptr,
                                                  const float* __restrict__ invdeg,
                                                  ushort* __restrict__ A) {
    int node = blockIdx.x * 4 + (threadIdx.x >> 6);
    if (node >= NN) return;
    int lane = threadIdx.x & 63;
    int b = rowptr[node], e = rowptr[node + 1];
    float ax = 0.f, ay = 0.f;
    for (int i = b; i < e; ++i) {
        int s = adj[i];
        unsigned int v = *reinterpret_cast<const unsigned int*>(&H[(size_t)s * HD + lane * 2]);
        ax += bflo(v);
        ay += bfhi(v);
    }
    float id = invdeg[node];
    *reinterpret_cast<unsigned int*>(&A[(size_t)node * HD + lane * 2]) = packbf(ax * id, ay * id);
}

// ---------------- output GEMM (fp32 dot): out[n,c] = sum_k h[n,k]*W[c,k] + b[c] ----------------
__global__ __launch_bounds__(256) void out_gemm(const ushort* __restrict__ H,
                                                const float* __restrict__ W,
                                                const float* __restrict__ B,
                                                float* __restrict__ out) {
    __shared__ float wlds[NCLS * 132];
    __shared__ float xlds[6 * HD];
    int t = threadIdx.x;
    for (int j = t; j < NCLS * HD; j += 256) {
        int c = j >> 7, k = j & 127;
        wlds[c * 132 + k] = W[j];
    }
    __syncthreads();
    int r = t / NCLS, c = t % NCLS;
    bool act = t < 6 * NCLS;
    float bv = act ? B[c] : 0.f;
    const int NT = (NN + 5) / 6;
    for (int tile = blockIdx.x; tile < NT; tile += gridDim.x) {
        int r0 = tile * 6;
        __syncthreads();
        const unsigned int* hp = reinterpret_cast<const unsigned int*>(H + (size_t)r0 * HD);
        for (int j = t; j < 3 * HD; j += 256) {  // 384 uints = 768 bf16
            unsigned int v = hp[j];
            xlds[j * 2] = bflo(v);
            xlds[j * 2 + 1] = bfhi(v);
        }
        __syncthreads();
        if (!act) continue;
        int row = r0 + r;
        if (row < NN) {
            float acc = 0.f;
#pragma unroll
            for (int kk = 0; kk < HD; kk += 4) {
                float4 w = *reinterpret_cast<float4*>(&wlds[c * 132 + kk]);
                float4 xv = *reinterpret_cast<float4*>(&xlds[r * HD + kk]);
                acc += w.x * xv.x + w.y * xv.y + w.z * xv.z + w.w * xv.w;
            }
            out[(size_t)row * NCLS + c] = acc + bv;
        }
    }
}

extern "C" void kernel_launch(void* const* d_in, const int* in_sizes, int n_in,
                              void* d_out, int out_size, void* d_ws, size_t ws_size,
                              hipStream_t stream) {
    const float* x = (const float*)d_in[0];
    const void* ei = d_in[1];
    const float* fc0_w = (const float*)d_in[2];
    const float* bn_scale = (const float*)d_in[4];
    const float* bn_bias = (const float*)d_in[5];
    const float* lin_l = (const float*)d_in[6];
    const float* lin_r = (const float*)d_in[7];
    const float* W_w = (const float*)d_in[8];
    const float* out_w = (const float*)d_in[10];
    const float* out_b = (const float*)d_in[11];
    float* out = (float*)d_out;

    // ---- workspace carve-up (256B aligned) ----
    char* p = (char*)d_ws;
    auto alloc = [&](size_t bytes) -> void* {
        void* r = (void*)p;
        p += (bytes + 255) & ~(size_t)255;
        return r;
    };
    int* deg = (int*)alloc(NN * 4);
    int* cursor = (int*)alloc(NN * 4);
    float* stats = (float*)alloc(3 * 256 * 4);  // [3][sum128|sumsq128]
    int* eflag = (int*)alloc(256);
    size_t ctrl_bytes = (size_t)(p - (char*)d_ws);
    int* esrc = (int*)alloc(EE * 4);
    int* edst = (int*)alloc(EE * 4);
    int* rowptr = (int*)alloc((NN + 1) * 4);
    float* invdeg = (float*)alloc(NN * 4);
    int* adj = (int*)alloc(EE * 4);
    int* bsum = (int*)alloc(256 * 4);
    int* boff = (int*)alloc(256 * 4);
    float* bnp = (float*)alloc(3 * 256 * 4);        // [3][scale128|bias128]
    ushort* Wcb = (ushort*)alloc(4 * HD * HD * 2);  // [layer][l/r][128][128] bf16
    ushort* wfc0 = (ushort*)alloc(HD * HD * 2);     // fc0_w bf16
    ushort* hpre = (ushort*)alloc((size_t)NN * HD * 2);  // pre-BN activations (bf16)
    ushort* hb = (ushort*)alloc((size_t)NN * HD * 2);
    ushort* aggb = (ushort*)alloc((size_t)NN * HD * 2);  // also reused as bf16 x

    hipMemsetAsync(d_ws, 0, ctrl_bytes, stream);

    // edge decode + degree
    detect_kernel<<<1, 256, 0, stream>>>(ei, eflag);
    decode_deg_kernel<<<1250, 512, 0, stream>>>(ei, eflag, esrc, edst, deg);

    // parallel scan -> rowptr/invdeg, then CSR fill
    deg_blocksum<<<196, 256, 0, stream>>>(deg, bsum);
    scan_bsums<<<1, 256, 0, stream>>>(bsum, boff);
    rowptr_fill<<<196, 256, 0, stream>>>(deg, boff, rowptr, invdeg);
    fill_kernel<<<1250, 512, 0, stream>>>(esrc, edst, rowptr, cursor, adj);

    // weights: combined (bf16) + fc0 (bf16); x -> bf16 (into aggb, free until layer0 agg)
    combine_w<<<dim3(HD, 4), HD, 0, stream>>>(W_w, lin_l, lin_r, Wcb);
    convw_kernel<<<64, 256, 0, stream>>>(fc0_w, wfc0);
    convx_kernel<<<3125, 256, 0, stream>>>(x, (ushort*)aggb);

    // fc0 + BN0 + ReLU (fc0_b dropped: cancelled by BN)
    gemm_mfma<false><<<GGRID, 512, 0, stream>>>((const ushort*)aggb, nullptr, wfc0, nullptr, hpre, stats);
    bn_fold<<<1, 128, 0, stream>>>(stats, bn_scale, bn_bias, bnp);
    bn_relu<<<3125, 256, 0, stream>>>(hpre, bnp, hb);

    for (int layer = 0; layer < 2; ++layer) {
        agg_kernel<<<(NN + 3) / 4, 256, 0, stream>>>(hb, adj, rowptr, invdeg, aggb);
        const ushort* Wl = Wcb + (size_t)(layer * 2 + 0) * HD * HD;
        const ushort* Wr = Wcb + (size_t)(layer * 2 + 1) * HD * HD;
        float* st = stats + (layer + 1) * 256;
        // fused: hpre = bf16(aggb@Wl^T + hb@Wr^T), stats fused (W_b dropped: cancelled by BN)
        gemm_mfma<true><<<GGRID, 512, 0, stream>>>(aggb, hb, Wl, Wr, hpre, st);
        float* bp = bnp + (layer + 1) * 256;
        bn_fold<<<1, 128, 0, stream>>>(st, bn_scale + (layer + 1) * HD, bn_bias + (layer + 1) * HD, bp);
        bn_relu<<<3125, 256, 0, stream>>>(hpre, bp, hb);
    }

    out_gemm<<<512, 256, 0, stream>>>(hb, out_w, out_b, out);
}

// Round 8
// 399.816 us; speedup vs baseline: 1.9473x; 1.2512x over previous
//
#include <hip/hip_runtime.h>
#include <hip/hip_bf16.h>

#define NN 50000
#define EE 640000
#define HD 128
#define NCLS 40
#define BN_EPS 1e-5f
#define GTILES 1563  // ceil(NN/32)
#define GGRID 782    // gemm grid: each block does tiles {bid, bid+GGRID}

typedef short bf16x8 __attribute__((ext_vector_type(8)));
typedef float f32x4 __attribute__((ext_vector_type(4)));

__device__ __forceinline__ short f2bf(float f) {
    __hip_bfloat16 h = __float2bfloat16(f);
    return *reinterpret_cast<short*>(&h);
}
__device__ __forceinline__ float bflo(unsigned int v) { return __uint_as_float(v << 16); }
__device__ __forceinline__ float bfhi(unsigned int v) { return __uint_as_float(v & 0xffff0000u); }
__device__ __forceinline__ unsigned int packbf(float a, float b) {
    return (unsigned)(unsigned short)f2bf(a) | ((unsigned)(unsigned short)f2bf(b) << 16);
}

// ---------------- edge_index width detect + decode (+degree count) ----------------
__global__ void detect_kernel(const void* __restrict__ ei, int* __restrict__ flag) {
    int t = threadIdx.x;  // 256
    const long long* p = (const long long*)ei;
    long long v = p[(size_t)t * (EE / 256)];
    if (v < 0 || v >= NN) atomicOr(flag, 1);  // flag=1 -> int32 data
}

__global__ void decode_deg_kernel(const void* __restrict__ ei, const int* __restrict__ flag,
                                  int* __restrict__ src, int* __restrict__ dst,
                                  int* __restrict__ deg) {
    bool narrow = (*flag != 0);
    for (int e = blockIdx.x * blockDim.x + threadIdx.x; e < EE; e += gridDim.x * blockDim.x) {
        int s, d;
        if (narrow) {
            const int* p = (const int*)ei;
            s = p[e]; d = p[EE + e];
        } else {
            const long long* p = (const long long*)ei;
            s = (int)p[e]; d = (int)p[EE + e];
        }
        src[e] = s;
        dst[e] = d;
        atomicAdd(&deg[d], 1);
    }
}

// ---------------- parallel scan: deg -> rowptr, invdeg ----------------
__global__ void deg_blocksum(const int* __restrict__ deg, int* __restrict__ bsum) {
    int i = blockIdx.x * 256 + threadIdx.x;
    int d = (i < NN) ? deg[i] : 0;
#pragma unroll
    for (int o = 32; o; o >>= 1) d += __shfl_down(d, o);
    __shared__ int ws[4];
    if ((threadIdx.x & 63) == 0) ws[threadIdx.x >> 6] = d;
    __syncthreads();
    if (threadIdx.x == 0) bsum[blockIdx.x] = ws[0] + ws[1] + ws[2] + ws[3];
}

__global__ void scan_bsums(const int* __restrict__ bsum, int* __restrict__ boff) {
    __shared__ int s[256];
    int t = threadIdx.x;
    int v = (t < 196) ? bsum[t] : 0;
    s[t] = v;
    __syncthreads();
    for (int o = 1; o < 256; o <<= 1) {
        int u = (t >= o) ? s[t - o] : 0;
        __syncthreads();
        s[t] += u;
        __syncthreads();
    }
    if (t < 196) boff[t] = s[t] - v;  // exclusive
}

__global__ void rowptr_fill(const int* __restrict__ deg, const int* __restrict__ boff,
                            int* __restrict__ rowptr, float* __restrict__ invdeg) {
    int b = blockIdx.x, t = threadIdx.x, i = b * 256 + t;
    int d = (i < NN) ? deg[i] : 0;
    __shared__ int s[256];
    s[t] = d;
    __syncthreads();
    for (int o = 1; o < 256; o <<= 1) {
        int u = (t >= o) ? s[t - o] : 0;
        __syncthreads();
        s[t] += u;
        __syncthreads();
    }
    int excl = s[t] - d + boff[b];
    if (i < NN) {
        rowptr[i] = excl;
        invdeg[i] = 1.0f / (float)(d > 1 ? d : 1);
        if (i == NN - 1) rowptr[NN] = excl + d;
    }
}

__global__ void fill_kernel(const int* __restrict__ src, const int* __restrict__ dst,
                            const int* __restrict__ rowptr, int* __restrict__ cursor,
                            int* __restrict__ adj) {
    for (int e = blockIdx.x * blockDim.x + threadIdx.x; e < EE; e += gridDim.x * blockDim.x) {
        int d = dst[e];
        int pos = atomicAdd(&cursor[d], 1);
        adj[rowptr[d] + pos] = src[e];
    }
}

// ---------------- weights: Wc[which] = bf16(W_w @ lin_{l/r}[layer]); fc0 -> bf16 ----------------
__global__ void combine_w(const float* __restrict__ Ww, const float* __restrict__ linl,
                          const float* __restrict__ linr, ushort* __restrict__ Wcb) {
    int k = threadIdx.x;
    int m = blockIdx.x;
    int which = blockIdx.y;  // layer = which>>1, l/r = which&1
    const float* lin = ((which & 1) ? linr : linl) + (which >> 1) * HD * HD;
    __shared__ float wrow[HD];
    wrow[k] = Ww[m * HD + k];
    __syncthreads();
    float acc = 0.f;
    for (int j = 0; j < HD; ++j) acc += wrow[j] * lin[j * HD + k];
    Wcb[which * HD * HD + m * HD + k] = (unsigned short)f2bf(acc);
}

__global__ void convw_kernel(const float* __restrict__ W, ushort* __restrict__ Wb) {
    int i = blockIdx.x * 256 + threadIdx.x;
    if (i < HD * HD) Wb[i] = (unsigned short)f2bf(W[i]);
}

// x (fp32) -> bf16, 8 elems/thread
__global__ __launch_bounds__(256) void convx_kernel(const float* __restrict__ X,
                                                    ushort* __restrict__ Xb) {
    int i = blockIdx.x * 256 + threadIdx.x;
    if (i >= NN * HD / 8) return;
    const float4* xp = reinterpret_cast<const float4*>(X) + (size_t)i * 2;
    float4 a = xp[0], b = xp[1];
    uint4 o;
    o.x = packbf(a.x, a.y);
    o.y = packbf(a.z, a.w);
    o.z = packbf(b.x, b.y);
    o.w = packbf(b.z, b.w);
    *reinterpret_cast<uint4*>(Xb + (size_t)i * 8) = o;
}

// ---------------- MFMA GEMM v4: coalesced LDS-staged, T14 pipelined, no stats ----------
// Y[n,m] = bf16( sum_k A1[n,k]*W1[m,k] (+ A2[n,k]*W2[m,k]) ). No bias (BN cancels it).
// Block = 256 thr = 4 waves; wave w owns cols [w*32, w*32+32) (cc=0,1 16-col groups).
// Tile = 32 rows x 128 cols bf16 = 8KB/matrix. Block does tiles {bid, bid+GGRID}.
// Weights: coalesced global -> LDS -> reg frags (one-time). A: reg-staged with
// PRE-SWIZZLED global source (rule 21) -> linear ds_write -> XOR-swizzled ds_read
// (q ^ ((row&7)<<4), ~2-way conflicts = free). Tile-1 loads issued before tile-0
// compute (T14 async-split) so HBM latency hides under MFMA.
template <bool DUAL>
__global__ __launch_bounds__(256) void gemm_mfma(const ushort* __restrict__ A1g,
                                                 const ushort* __restrict__ A2g,
                                                 const ushort* __restrict__ W1,
                                                 const ushort* __restrict__ W2,
                                                 ushort* __restrict__ Y) {
    __shared__ __align__(16) char lds[32768];
    const int t = threadIdx.x;
    const int l = t & 63, w = t >> 6;
    const int lr = l & 15, lg = l >> 4;
    constexpr int BUFSZ = DUAL ? 16384 : 8192;

    // ---- weight setup: stage 32KB coalesced into LDS, extract frags to regs ----
    bf16x8 bw1[2][4], bw2[2][4];
    {
        const uint4* srcw = (const uint4*)W1;
        for (int i = t; i < 2048; i += 256) ((uint4*)lds)[i] = srcw[i];
        __syncthreads();
#pragma unroll
        for (int cc = 0; cc < 2; ++cc)
#pragma unroll
            for (int kk = 0; kk < 4; ++kk)
                bw1[cc][kk] = *(const bf16x8*)&lds[((w * 2 + cc) * 16 + lr) * 256 + kk * 64 + lg * 16];
        if constexpr (DUAL) {
            __syncthreads();
            const uint4* srcw2 = (const uint4*)W2;
            for (int i = t; i < 2048; i += 256) ((uint4*)lds)[i] = srcw2[i];
            __syncthreads();
#pragma unroll
            for (int cc = 0; cc < 2; ++cc)
#pragma unroll
                for (int kk = 0; kk < 4; ++kk)
                    bw2[cc][kk] = *(const bf16x8*)&lds[((w * 2 + cc) * 16 + lr) * 256 + kk * 64 + lg * 16];
        }
        __syncthreads();
    }

    const int t0 = blockIdx.x;
    const int t1 = blockIdx.x + GGRID;
    const bool has2 = (t1 < GTILES);

    // staging helpers (all-static indexing)
    uint4 s1a[2], s2a[2];
    auto stage_load = [&](int tile, uint4* st1, uint4* st2) {
#pragma unroll
        for (int s = 0; s < 2; ++s) {
            int o = s * 4096 + t * 16;                 // linear dest byte in A-region
            int po = o ^ (((o >> 8) & 7) << 4);        // pre-swizzled source byte
            int grow = tile * 32 + (po >> 8);
            if (grow > NN - 1) grow = NN - 1;
            st1[s] = *(const uint4*)((const char*)A1g + (size_t)grow * 256 + (po & 255));
            if constexpr (DUAL)
                st2[s] = *(const uint4*)((const char*)A2g + (size_t)grow * 256 + (po & 255));
        }
    };
    auto stage_write = [&](int buf, const uint4* st1, const uint4* st2) {
        char* base = lds + buf * BUFSZ;
#pragma unroll
        for (int s = 0; s < 2; ++s) {
            *(uint4*)(base + s * 4096 + t * 16) = st1[s];
            if constexpr (DUAL) *(uint4*)(base + 8192 + s * 4096 + t * 16) = st2[s];
        }
    };
    auto compute = [&](int tile, int buf) {
        const char* base = lds + buf * BUFSZ;
        f32x4 acc[2][2] = {};
#pragma unroll
        for (int rf = 0; rf < 2; ++rf) {
            int rowb = (rf * 16 + lr) * 256;
            int sw = (lr & 7) << 4;
            bf16x8 a1[4], a2[4];
#pragma unroll
            for (int kk = 0; kk < 4; ++kk) {
                int q = rowb + ((kk * 64 + lg * 16) ^ sw);
                a1[kk] = *(const bf16x8*)(base + q);
                if constexpr (DUAL) a2[kk] = *(const bf16x8*)(base + 8192 + q);
            }
#pragma unroll
            for (int kk = 0; kk < 4; ++kk)
#pragma unroll
                for (int cc = 0; cc < 2; ++cc) {
                    acc[rf][cc] = __builtin_amdgcn_mfma_f32_16x16x32_bf16(bw1[cc][kk], a1[kk], acc[rf][cc], 0, 0, 0);
                    if constexpr (DUAL)
                        acc[rf][cc] = __builtin_amdgcn_mfma_f32_16x16x32_bf16(bw2[cc][kk], a2[kk], acc[rf][cc], 0, 0, 0);
                }
        }
#pragma unroll
        for (int rf = 0; rf < 2; ++rf) {
            int row = tile * 32 + rf * 16 + lr;
            if (row < NN) {
#pragma unroll
                for (int cc = 0; cc < 2; ++cc) {
                    uint2 o;
                    o.x = packbf(acc[rf][cc][0], acc[rf][cc][1]);
                    o.y = packbf(acc[rf][cc][2], acc[rf][cc][3]);
                    *(uint2*)&Y[(size_t)row * HD + (w * 2 + cc) * 16 + lg * 4] = o;
                }
            }
        }
    };

    // ---- pipeline: stage t0; issue t1 loads; compute t0 (t1 in flight); write t1; compute ----
    stage_load(t0, s1a, s2a);
    stage_write(0, s1a, s2a);
    if (has2) stage_load(t1, s1a, s2a);  // in flight during compute(t0)
    __syncthreads();
    compute(t0, 0);
    if (has2) {
        stage_write(1, s1a, s2a);
        __syncthreads();
        compute(t1, 1);
    }
}

// ---------------- BN stats: per-block column partials (no global atomics) ----------------
// parts layout: parts[j*256 + b], j<128 = col-sum, j>=128 = col-sqsum, b = block
__global__ __launch_bounds__(256) void stat_part(const ushort* __restrict__ Hp,
                                                 float* __restrict__ parts) {
    __shared__ float s1[HD], s2[HD];
    int tid = threadIdx.x, bid = blockIdx.x;
    if (tid < HD) { s1[tid] = 0.f; s2[tid] = 0.f; }
    __syncthreads();
    int cb = (tid & 15) * 8;
    float ps[8] = {}, pq[8] = {};
    const uint4* H4 = (const uint4*)Hp;
    for (int i = bid * 256 + tid; i < NN * HD / 8; i += 256 * 256) {
        uint4 v = H4[i];
        float e0 = bflo(v.x), e1 = bfhi(v.x), e2 = bflo(v.y), e3 = bfhi(v.y);
        float e4 = bflo(v.z), e5 = bfhi(v.z), e6 = bflo(v.w), e7 = bfhi(v.w);
        ps[0] += e0; pq[0] += e0 * e0;
        ps[1] += e1; pq[1] += e1 * e1;
        ps[2] += e2; pq[2] += e2 * e2;
        ps[3] += e3; pq[3] += e3 * e3;
        ps[4] += e4; pq[4] += e4 * e4;
        ps[5] += e5; pq[5] += e5 * e5;
        ps[6] += e6; pq[6] += e6 * e6;
        ps[7] += e7; pq[7] += e7 * e7;
    }
#pragma unroll
    for (int c = 0; c < 8; ++c) {
        atomicAdd(&s1[cb + c], ps[c]);
        atomicAdd(&s2[cb + c], pq[c]);
    }
    __syncthreads();
    if (tid < HD) {
        parts[tid * 256 + bid] = s1[tid];
        parts[(HD + tid) * 256 + bid] = s2[tid];
    }
}

// ---------------- BN fold (reduces partials) ----------------
__global__ void bn_fold(const float* __restrict__ parts, const float* __restrict__ scale,
                        const float* __restrict__ bias, float* __restrict__ bnp) {
    int t = threadIdx.x;  // 128
    float s = 0.f, q = 0.f;
    const float4* ps = (const float4*)(parts + t * 256);
    const float4* pq = (const float4*)(parts + (HD + t) * 256);
    for (int b = 0; b < 64; ++b) {
        float4 a = ps[b], c = pq[b];
        s += a.x + a.y + a.z + a.w;
        q += c.x + c.y + c.z + c.w;
    }
    float mu = s * (1.0f / NN);
    float var = q * (1.0f / NN) - mu * mu;
    float sc = scale[t] * rsqrtf(var + BN_EPS);
    bnp[t] = sc;
    bnp[HD + t] = bias[t] - mu * sc;
}

__global__ __launch_bounds__(256) void bn_relu(const ushort* __restrict__ Hp,
                                               const float* __restrict__ bnp,
                                               ushort* __restrict__ Hb) {
    int i = blockIdx.x * 256 + threadIdx.x;  // one thread per 8 features
    if (i >= NN * HD / 8) return;
    int mb = (i & 15) * 8;
    uint4 v = reinterpret_cast<const uint4*>(Hp)[i];
    float4 sa = *reinterpret_cast<const float4*>(&bnp[mb]);
    float4 sb = *reinterpret_cast<const float4*>(&bnp[mb + 4]);
    float4 ba = *reinterpret_cast<const float4*>(&bnp[HD + mb]);
    float4 bb = *reinterpret_cast<const float4*>(&bnp[HD + mb + 4]);
    float v0 = fmaxf(bflo(v.x) * sa.x + ba.x, 0.f);
    float v1 = fmaxf(bfhi(v.x) * sa.y + ba.y, 0.f);
    float v2 = fmaxf(bflo(v.y) * sa.z + ba.z, 0.f);
    float v3 = fmaxf(bfhi(v.y) * sa.w + ba.w, 0.f);
    float v4 = fmaxf(bflo(v.z) * sb.x + bb.x, 0.f);
    float v5 = fmaxf(bfhi(v.z) * sb.y + bb.y, 0.f);
    float v6 = fmaxf(bflo(v.w) * sb.z + bb.z, 0.f);
    float v7 = fmaxf(bfhi(v.w) * sb.w + bb.w, 0.f);
    uint4 o;
    o.x = packbf(v0, v1);
    o.y = packbf(v2, v3);
    o.z = packbf(v4, v5);
    o.w = packbf(v6, v7);
    *reinterpret_cast<uint4*>(Hb + (size_t)i * 8) = o;
}

// ---------------- aggregation (bf16 in/out): agg[n] = invdeg[n]*sum h[adj] ----------------
__global__ __launch_bounds__(256) void agg_kernel(const ushort* __restrict__ H,
                                                  const int* __restrict__ adj,
                                                  const int* __restrict__ rowptr,
                                                  const float* __restrict__ invdeg,
                                                  ushort* __restrict__ A) {
    int node = blockIdx.x * 4 + (threadIdx.x >> 6);
    if (node >= NN) return;
    int lane = threadIdx.x & 63;
    int b = rowptr[node], e = rowptr[node + 1];
    float ax = 0.f, ay = 0.f;
    for (int i = b; i < e; ++i) {
        int s = adj[i];
        unsigned int v = *reinterpret_cast<const unsigned int*>(&H[(size_t)s * HD + lane * 2]);
        ax += bflo(v);
        ay += bfhi(v);
    }
    float id = invdeg[node];
    *reinterpret_cast<unsigned int*>(&A[(size_t)node * HD + lane * 2]) = packbf(ax * id, ay * id);
}

// ---------------- output GEMM (fp32 dot): out[n,c] = sum_k h[n,k]*W[c,k] + b[c] ----------------
__global__ __launch_bounds__(256) void out_gemm(const ushort* __restrict__ H,
                                                const float* __restrict__ W,
                                                const float* __restrict__ B,
                                                float* __restrict__ out) {
    __shared__ float wlds[NCLS * 132];
    __shared__ float xlds[6 * HD];
    int t = threadIdx.x;
    for (int j = t; j < NCLS * HD; j += 256) {
        int c = j >> 7, k = j & 127;
        wlds[c * 132 + k] = W[j];
    }
    __syncthreads();
    int r = t / NCLS, c = t % NCLS;
    bool act = t < 6 * NCLS;
    float bv = act ? B[c] : 0.f;
    const int NT = (NN + 5) / 6;
    for (int tile = blockIdx.x; tile < NT; tile += gridDim.x) {
        int r0 = tile * 6;
        __syncthreads();
        const unsigned int* hp = reinterpret_cast<const unsigned int*>(H + (size_t)r0 * HD);
        for (int j = t; j < 3 * HD; j += 256) {  // 384 uints = 768 bf16
            unsigned int v = hp[j];
            xlds[j * 2] = bflo(v);
            xlds[j * 2 + 1] = bfhi(v);
        }
        __syncthreads();
        if (!act) continue;
        int row = r0 + r;
        if (row < NN) {
            float acc = 0.f;
#pragma unroll
            for (int kk = 0; kk < HD; kk += 4) {
                float4 w = *reinterpret_cast<float4*>(&wlds[c * 132 + kk]);
                float4 xv = *reinterpret_cast<float4*>(&xlds[r * HD + kk]);
                acc += w.x * xv.x + w.y * xv.y + w.z * xv.z + w.w * xv.w;
            }
            out[(size_t)row * NCLS + c] = acc + bv;
        }
    }
}

extern "C" void kernel_launch(void* const* d_in, const int* in_sizes, int n_in,
                              void* d_out, int out_size, void* d_ws, size_t ws_size,
                              hipStream_t stream) {
    const float* x = (const float*)d_in[0];
    const void* ei = d_in[1];
    const float* fc0_w = (const float*)d_in[2];
    const float* bn_scale = (const float*)d_in[4];
    const float* bn_bias = (const float*)d_in[5];
    const float* lin_l = (const float*)d_in[6];
    const float* lin_r = (const float*)d_in[7];
    const float* W_w = (const float*)d_in[8];
    const float* out_w = (const float*)d_in[10];
    const float* out_b = (const float*)d_in[11];
    float* out = (float*)d_out;

    // ---- workspace carve-up (256B aligned) ----
    char* p = (char*)d_ws;
    auto alloc = [&](size_t bytes) -> void* {
        void* r = (void*)p;
        p += (bytes + 255) & ~(size_t)255;
        return r;
    };
    int* deg = (int*)alloc(NN * 4);
    int* cursor = (int*)alloc(NN * 4);
    int* eflag = (int*)alloc(256);
    size_t ctrl_bytes = (size_t)(p - (char*)d_ws);
    int* esrc = (int*)alloc(EE * 4);
    int* edst = (int*)alloc(EE * 4);
    int* rowptr = (int*)alloc((NN + 1) * 4);
    float* invdeg = (float*)alloc(NN * 4);
    int* adj = (int*)alloc(EE * 4);
    int* bsum = (int*)alloc(256 * 4);
    int* boff = (int*)alloc(256 * 4);
    float* parts = (float*)alloc(256 * 256 * 4);    // stats partials [256col*2][256blk]
    float* bnp = (float*)alloc(3 * 256 * 4);        // [3][scale128|bias128]
    ushort* Wcb = (ushort*)alloc(4 * HD * HD * 2);  // [layer][l/r][128][128] bf16
    ushort* wfc0 = (ushort*)alloc(HD * HD * 2);     // fc0_w bf16
    ushort* hpre = (ushort*)alloc((size_t)NN * HD * 2);  // pre-BN activations (bf16)
    ushort* hb = (ushort*)alloc((size_t)NN * HD * 2);
    ushort* aggb = (ushort*)alloc((size_t)NN * HD * 2);  // also reused as bf16 x

    hipMemsetAsync(d_ws, 0, ctrl_bytes, stream);

    // edge decode + degree
    detect_kernel<<<1, 256, 0, stream>>>(ei, eflag);
    decode_deg_kernel<<<1250, 512, 0, stream>>>(ei, eflag, esrc, edst, deg);

    // parallel scan -> rowptr/invdeg, then CSR fill
    deg_blocksum<<<196, 256, 0, stream>>>(deg, bsum);
    scan_bsums<<<1, 256, 0, stream>>>(bsum, boff);
    rowptr_fill<<<196, 256, 0, stream>>>(deg, boff, rowptr, invdeg);
    fill_kernel<<<1250, 512, 0, stream>>>(esrc, edst, rowptr, cursor, adj);

    // weights: combined (bf16) + fc0 (bf16); x -> bf16 (into aggb, free until layer0 agg)
    combine_w<<<dim3(HD, 4), HD, 0, stream>>>(W_w, lin_l, lin_r, Wcb);
    convw_kernel<<<64, 256, 0, stream>>>(fc0_w, wfc0);
    convx_kernel<<<3125, 256, 0, stream>>>(x, (ushort*)aggb);

    // fc0 + BN0 + ReLU (fc0_b dropped: cancelled by BN)
    gemm_mfma<false><<<GGRID, 256, 0, stream>>>((const ushort*)aggb, nullptr, wfc0, nullptr, hpre);
    stat_part<<<256, 256, 0, stream>>>(hpre, parts);
    bn_fold<<<1, 128, 0, stream>>>(parts, bn_scale, bn_bias, bnp);
    bn_relu<<<3125, 256, 0, stream>>>(hpre, bnp, hb);

    for (int layer = 0; layer < 2; ++layer) {
        agg_kernel<<<(NN + 3) / 4, 256, 0, stream>>>(hb, adj, rowptr, invdeg, aggb);
        const ushort* Wl = Wcb + (size_t)(layer * 2 + 0) * HD * HD;
        const ushort* Wr = Wcb + (size_t)(layer * 2 + 1) * HD * HD;
        // fused: hpre = bf16(aggb@Wl^T + hb@Wr^T)  (W_b dropped: cancelled by BN)
        gemm_mfma<true><<<GGRID, 256, 0, stream>>>(aggb, hb, Wl, Wr, hpre);
        stat_part<<<256, 256, 0, stream>>>(hpre, parts);
        float* bp = bnp + (layer + 1) * 256;
        bn_fold<<<1, 128, 0, stream>>>(parts, bn_scale + (layer + 1) * HD, bn_bias + (layer + 1) * HD, bp);
        bn_relu<<<3125, 256, 0, stream>>>(hpre, bp, hb);
    }

    out_gemm<<<512, 256, 0, stream>>>(hb, out_w, out_b, out);
}

// Round 9
// 272.683 us; speedup vs baseline: 2.8552x; 1.4662x over previous
//
#include <hip/hip_runtime.h>
#include <hip/hip_bf16.h>

#define NN 50000
#define EE 640000
#define HD 128
#define NCLS 40
#define BN_EPS 1e-5f
#define GTILES 1563  // ceil(NN/32)
#define GGRID 782    // gemm grid: each block does tiles {bid, bid+GGRID}

typedef short bf16x8 __attribute__((ext_vector_type(8)));
typedef float f32x4 __attribute__((ext_vector_type(4)));

__device__ __forceinline__ short f2bf(float f) {
    __hip_bfloat16 h = __float2bfloat16(f);
    return *reinterpret_cast<short*>(&h);
}
__device__ __forceinline__ float bflo(unsigned int v) { return __uint_as_float(v << 16); }
__device__ __forceinline__ float bfhi(unsigned int v) { return __uint_as_float(v & 0xffff0000u); }
__device__ __forceinline__ unsigned int packbf(float a, float b) {
    return (unsigned)(unsigned short)f2bf(a) | ((unsigned)(unsigned short)f2bf(b) << 16);
}

// ---------------- edge_index width detect + decode (+degree count) ----------------
__global__ void detect_kernel(const void* __restrict__ ei, int* __restrict__ flag) {
    int t = threadIdx.x;  // 256
    const long long* p = (const long long*)ei;
    long long v = p[(size_t)t * (EE / 256)];
    if (v < 0 || v >= NN) atomicOr(flag, 1);  // flag=1 -> int32 data
}

__global__ void decode_deg_kernel(const void* __restrict__ ei, const int* __restrict__ flag,
                                  int* __restrict__ src, int* __restrict__ dst,
                                  int* __restrict__ deg) {
    bool narrow = (*flag != 0);
    for (int e = blockIdx.x * blockDim.x + threadIdx.x; e < EE; e += gridDim.x * blockDim.x) {
        int s, d;
        if (narrow) {
            const int* p = (const int*)ei;
            s = p[e]; d = p[EE + e];
        } else {
            const long long* p = (const long long*)ei;
            s = (int)p[e]; d = (int)p[EE + e];
        }
        src[e] = s;
        dst[e] = d;
        atomicAdd(&deg[d], 1);
    }
}

// ---------------- parallel scan: deg -> rowptr, invdeg ----------------
__global__ void deg_blocksum(const int* __restrict__ deg, int* __restrict__ bsum) {
    int i = blockIdx.x * 256 + threadIdx.x;
    int d = (i < NN) ? deg[i] : 0;
#pragma unroll
    for (int o = 32; o; o >>= 1) d += __shfl_down(d, o);
    __shared__ int ws[4];
    if ((threadIdx.x & 63) == 0) ws[threadIdx.x >> 6] = d;
    __syncthreads();
    if (threadIdx.x == 0) bsum[blockIdx.x] = ws[0] + ws[1] + ws[2] + ws[3];
}

__global__ void scan_bsums(const int* __restrict__ bsum, int* __restrict__ boff) {
    __shared__ int s[256];
    int t = threadIdx.x;
    int v = (t < 196) ? bsum[t] : 0;
    s[t] = v;
    __syncthreads();
    for (int o = 1; o < 256; o <<= 1) {
        int u = (t >= o) ? s[t - o] : 0;
        __syncthreads();
        s[t] += u;
        __syncthreads();
    }
    if (t < 196) boff[t] = s[t] - v;  // exclusive
}

__global__ void rowptr_fill(const int* __restrict__ deg, const int* __restrict__ boff,
                            int* __restrict__ rowptr, float* __restrict__ invdeg) {
    int b = blockIdx.x, t = threadIdx.x, i = b * 256 + t;
    int d = (i < NN) ? deg[i] : 0;
    __shared__ int s[256];
    s[t] = d;
    __syncthreads();
    for (int o = 1; o < 256; o <<= 1) {
        int u = (t >= o) ? s[t - o] : 0;
        __syncthreads();
        s[t] += u;
        __syncthreads();
    }
    int excl = s[t] - d + boff[b];
    if (i < NN) {
        rowptr[i] = excl;
        invdeg[i] = 1.0f / (float)(d > 1 ? d : 1);
        if (i == NN - 1) rowptr[NN] = excl + d;
    }
}

__global__ void fill_kernel(const int* __restrict__ src, const int* __restrict__ dst,
                            const int* __restrict__ rowptr, int* __restrict__ cursor,
                            int* __restrict__ adj) {
    for (int e = blockIdx.x * blockDim.x + threadIdx.x; e < EE; e += gridDim.x * blockDim.x) {
        int d = dst[e];
        int pos = atomicAdd(&cursor[d], 1);
        adj[rowptr[d] + pos] = src[e];
    }
}

// ---------------- weights: Wc[which] = bf16(W_w @ lin_{l/r}[layer]); fc0 -> bf16 ----------------
__global__ void combine_w(const float* __restrict__ Ww, const float* __restrict__ linl,
                          const float* __restrict__ linr, ushort* __restrict__ Wcb) {
    int k = threadIdx.x;
    int m = blockIdx.x;
    int which = blockIdx.y;  // layer = which>>1, l/r = which&1
    const float* lin = ((which & 1) ? linr : linl) + (which >> 1) * HD * HD;
    __shared__ float wrow[HD];
    wrow[k] = Ww[m * HD + k];
    __syncthreads();
    float acc = 0.f;
    for (int j = 0; j < HD; ++j) acc += wrow[j] * lin[j * HD + k];
    Wcb[which * HD * HD + m * HD + k] = (unsigned short)f2bf(acc);
}

__global__ void convw_kernel(const float* __restrict__ W, ushort* __restrict__ Wb) {
    int i = blockIdx.x * 256 + threadIdx.x;
    if (i < HD * HD) Wb[i] = (unsigned short)f2bf(W[i]);
}

// x (fp32) -> bf16, 8 elems/thread
__global__ __launch_bounds__(256) void convx_kernel(const float* __restrict__ X,
                                                    ushort* __restrict__ Xb) {
    int i = blockIdx.x * 256 + threadIdx.x;
    if (i >= NN * HD / 8) return;
    const float4* xp = reinterpret_cast<const float4*>(X) + (size_t)i * 2;
    float4 a = xp[0], b = xp[1];
    uint4 o;
    o.x = packbf(a.x, a.y);
    o.y = packbf(a.z, a.w);
    o.z = packbf(b.x, b.y);
    o.w = packbf(b.z, b.w);
    *reinterpret_cast<uint4*>(Xb + (size_t)i * 8) = o;
}

// ---------------- MFMA GEMM v5: coalesced LDS-staged, pipelined, fused stat partials ----
// Y[n,m] = bf16( sum_k A1[n,k]*W1[m,k] (+ A2[n,k]*W2[m,k]) ). No bias (BN cancels it).
// Per-column sum/sqsum partials from the fp32 accumulator -> parts[col][bid] (no atomics).
template <bool DUAL>
__global__ __launch_bounds__(256) void gemm_mfma(const ushort* __restrict__ A1g,
                                                 const ushort* __restrict__ A2g,
                                                 const ushort* __restrict__ W1,
                                                 const ushort* __restrict__ W2,
                                                 ushort* __restrict__ Y,
                                                 float* __restrict__ parts) {
    __shared__ __align__(16) char lds[32768];
    const int t = threadIdx.x;
    const int l = t & 63, w = t >> 6;
    const int lr = l & 15, lg = l >> 4;
    constexpr int BUFSZ = DUAL ? 16384 : 8192;

    // ---- weight setup: stage 32KB coalesced into LDS, extract frags to regs ----
    bf16x8 bw1[2][4], bw2[2][4];
    {
        const uint4* srcw = (const uint4*)W1;
        for (int i = t; i < 2048; i += 256) ((uint4*)lds)[i] = srcw[i];
        __syncthreads();
#pragma unroll
        for (int cc = 0; cc < 2; ++cc)
#pragma unroll
            for (int kk = 0; kk < 4; ++kk)
                bw1[cc][kk] = *(const bf16x8*)&lds[((w * 2 + cc) * 16 + lr) * 256 + kk * 64 + lg * 16];
        if constexpr (DUAL) {
            __syncthreads();
            const uint4* srcw2 = (const uint4*)W2;
            for (int i = t; i < 2048; i += 256) ((uint4*)lds)[i] = srcw2[i];
            __syncthreads();
#pragma unroll
            for (int cc = 0; cc < 2; ++cc)
#pragma unroll
                for (int kk = 0; kk < 4; ++kk)
                    bw2[cc][kk] = *(const bf16x8*)&lds[((w * 2 + cc) * 16 + lr) * 256 + kk * 64 + lg * 16];
        }
        __syncthreads();
    }

    const int t0 = blockIdx.x;
    const int t1 = blockIdx.x + GGRID;
    const bool has2 = (t1 < GTILES);

    f32x4 ss[2] = {}, sq[2] = {};

    // staging helpers (all-static indexing)
    uint4 s1a[2], s2a[2];
    auto stage_load = [&](int tile, uint4* st1, uint4* st2) {
#pragma unroll
        for (int s = 0; s < 2; ++s) {
            int o = s * 4096 + t * 16;                 // linear dest byte in A-region
            int po = o ^ (((o >> 8) & 7) << 4);        // pre-swizzled source byte
            int grow = tile * 32 + (po >> 8);
            if (grow > NN - 1) grow = NN - 1;
            st1[s] = *(const uint4*)((const char*)A1g + (size_t)grow * 256 + (po & 255));
            if constexpr (DUAL)
                st2[s] = *(const uint4*)((const char*)A2g + (size_t)grow * 256 + (po & 255));
        }
    };
    auto stage_write = [&](int buf, const uint4* st1, const uint4* st2) {
        char* base = lds + buf * BUFSZ;
#pragma unroll
        for (int s = 0; s < 2; ++s) {
            *(uint4*)(base + s * 4096 + t * 16) = st1[s];
            if constexpr (DUAL) *(uint4*)(base + 8192 + s * 4096 + t * 16) = st2[s];
        }
    };
    auto compute = [&](int tile, int buf) {
        const char* base = lds + buf * BUFSZ;
        f32x4 acc[2][2] = {};
#pragma unroll
        for (int rf = 0; rf < 2; ++rf) {
            int rowb = (rf * 16 + lr) * 256;
            int sw = (lr & 7) << 4;
            bf16x8 a1[4], a2[4];
#pragma unroll
            for (int kk = 0; kk < 4; ++kk) {
                int q = rowb + ((kk * 64 + lg * 16) ^ sw);
                a1[kk] = *(const bf16x8*)(base + q);
                if constexpr (DUAL) a2[kk] = *(const bf16x8*)(base + 8192 + q);
            }
#pragma unroll
            for (int kk = 0; kk < 4; ++kk)
#pragma unroll
                for (int cc = 0; cc < 2; ++cc) {
                    acc[rf][cc] = __builtin_amdgcn_mfma_f32_16x16x32_bf16(bw1[cc][kk], a1[kk], acc[rf][cc], 0, 0, 0);
                    if constexpr (DUAL)
                        acc[rf][cc] = __builtin_amdgcn_mfma_f32_16x16x32_bf16(bw2[cc][kk], a2[kk], acc[rf][cc], 0, 0, 0);
                }
        }
#pragma unroll
        for (int rf = 0; rf < 2; ++rf) {
            int row = tile * 32 + rf * 16 + lr;
            if (row < NN) {
#pragma unroll
                for (int cc = 0; cc < 2; ++cc) {
                    f32x4 v = acc[rf][cc];
                    uint2 o;
                    o.x = packbf(v[0], v[1]);
                    o.y = packbf(v[2], v[3]);
                    *(uint2*)&Y[(size_t)row * HD + (w * 2 + cc) * 16 + lg * 4] = o;
                    ss[cc] += v;
                    sq[cc] += v * v;
                }
            }
        }
    };

    // ---- pipeline: stage t0; issue t1 loads; compute t0 (t1 in flight); write t1; compute ----
    stage_load(t0, s1a, s2a);
    stage_write(0, s1a, s2a);
    if (has2) stage_load(t1, s1a, s2a);  // in flight during compute(t0)
    __syncthreads();
    compute(t0, 0);
    if (has2) {
        stage_write(1, s1a, s2a);
        __syncthreads();
        compute(t1, 1);
    }

    // ---- stat partials: reduce over the 16 lr lanes (rows), write parts[col][bid] ----
#pragma unroll
    for (int cc = 0; cc < 2; ++cc)
#pragma unroll
        for (int j = 0; j < 4; ++j) {
            float a = ss[cc][j], b = sq[cc][j];
#pragma unroll
            for (int m = 1; m < 16; m <<= 1) {
                a += __shfl_xor(a, m);
                b += __shfl_xor(b, m);
            }
            if (lr == 0) {
                int col = (w * 2 + cc) * 16 + lg * 4 + j;
                parts[(size_t)col * GGRID + blockIdx.x] = a;
                parts[(size_t)(HD + col) * GGRID + blockIdx.x] = b;
            }
        }
}

// ---------------- BN fold v2: block j reduces 782 partials for col j -> bnp ----------------
__global__ __launch_bounds__(256) void bn_fold2(const float* __restrict__ parts,
                                                const float* __restrict__ scale,
                                                const float* __restrict__ bias,
                                                float* __restrict__ bnp) {
    __shared__ float r1[256], r2[256];
    int j = blockIdx.x;   // 0..127 column
    int t = threadIdx.x;  // 256
    float a = 0.f, b = 0.f;
    for (int i = t; i < GGRID; i += 256) {
        a += parts[(size_t)j * GGRID + i];
        b += parts[(size_t)(HD + j) * GGRID + i];
    }
    r1[t] = a; r2[t] = b;
    __syncthreads();
    for (int o = 128; o; o >>= 1) {
        if (t < o) { r1[t] += r1[t + o]; r2[t] += r2[t + o]; }
        __syncthreads();
    }
    if (t == 0) {
        float mu = r1[0] * (1.0f / NN);
        float var = r2[0] * (1.0f / NN) - mu * mu;
        float sc = scale[j] * rsqrtf(var + BN_EPS);
        bnp[j] = sc;
        bnp[HD + j] = bias[j] - mu * sc;
    }
}

__global__ __launch_bounds__(256) void bn_relu(const ushort* __restrict__ Hp,
                                               const float* __restrict__ bnp,
                                               ushort* __restrict__ Hb) {
    int i = blockIdx.x * 256 + threadIdx.x;  // one thread per 8 features
    if (i >= NN * HD / 8) return;
    int mb = (i & 15) * 8;
    uint4 v = reinterpret_cast<const uint4*>(Hp)[i];
    float4 sa = *reinterpret_cast<const float4*>(&bnp[mb]);
    float4 sb = *reinterpret_cast<const float4*>(&bnp[mb + 4]);
    float4 ba = *reinterpret_cast<const float4*>(&bnp[HD + mb]);
    float4 bb = *reinterpret_cast<const float4*>(&bnp[HD + mb + 4]);
    float v0 = fmaxf(bflo(v.x) * sa.x + ba.x, 0.f);
    float v1 = fmaxf(bfhi(v.x) * sa.y + ba.y, 0.f);
    float v2 = fmaxf(bflo(v.y) * sa.z + ba.z, 0.f);
    float v3 = fmaxf(bfhi(v.y) * sa.w + ba.w, 0.f);
    float v4 = fmaxf(bflo(v.z) * sb.x + bb.x, 0.f);
    float v5 = fmaxf(bfhi(v.z) * sb.y + bb.y, 0.f);
    float v6 = fmaxf(bflo(v.w) * sb.z + bb.z, 0.f);
    float v7 = fmaxf(bfhi(v.w) * sb.w + bb.w, 0.f);
    uint4 o;
    o.x = packbf(v0, v1);
    o.y = packbf(v2, v3);
    o.z = packbf(v4, v5);
    o.w = packbf(v6, v7);
    *reinterpret_cast<uint4*>(Hb + (size_t)i * 8) = o;
}

// ---------------- aggregation v2: 8 neighbors in flight per wave-iteration ----------------
// Wave per node. lane = (slot 0..3)*16 + col 0..15; per iter, lane loads 16B of row
// adj[i+slot] and 16B of row adj[i+4+slot] (8 rows/iter in flight). Cross-slot reduce
// via shfl_xor(16/32); slot-0 group writes the 256B bf16 row coalesced.
__global__ __launch_bounds__(256) void agg_kernel(const ushort* __restrict__ H,
                                                  const int* __restrict__ adj,
                                                  const int* __restrict__ rowptr,
                                                  const float* __restrict__ invdeg,
                                                  ushort* __restrict__ A) {
    int node = blockIdx.x * 4 + (threadIdx.x >> 6);
    if (node >= NN) return;
    int l = threadIdx.x & 63;
    int slot = l >> 4, col = l & 15;
    int b = rowptr[node], e = rowptr[node + 1];
    float id = invdeg[node];
    float acc[8] = {};
    for (int i = b; i < e; i += 8) {
        int i0 = i + slot, i1 = i + 4 + slot;
        bool v0 = i0 < e, v1 = i1 < e;
        int s0 = adj[v0 ? i0 : i];
        int s1 = adj[v1 ? i1 : i];
        uint4 a = *(const uint4*)&H[(size_t)s0 * HD + col * 8];
        uint4 c = *(const uint4*)&H[(size_t)s1 * HD + col * 8];
        float m0 = v0 ? 1.f : 0.f, m1 = v1 ? 1.f : 0.f;
        acc[0] += bflo(a.x) * m0 + bflo(c.x) * m1;
        acc[1] += bfhi(a.x) * m0 + bfhi(c.x) * m1;
        acc[2] += bflo(a.y) * m0 + bflo(c.y) * m1;
        acc[3] += bfhi(a.y) * m0 + bfhi(c.y) * m1;
        acc[4] += bflo(a.z) * m0 + bflo(c.z) * m1;
        acc[5] += bfhi(a.z) * m0 + bfhi(c.z) * m1;
        acc[6] += bflo(a.w) * m0 + bflo(c.w) * m1;
        acc[7] += bfhi(a.w) * m0 + bfhi(c.w) * m1;
    }
#pragma unroll
    for (int c2 = 0; c2 < 8; ++c2) {
        acc[c2] += __shfl_xor(acc[c2], 16);
        acc[c2] += __shfl_xor(acc[c2], 32);
    }
    if (slot == 0) {
        uint4 o;
        o.x = packbf(acc[0] * id, acc[1] * id);
        o.y = packbf(acc[2] * id, acc[3] * id);
        o.z = packbf(acc[4] * id, acc[5] * id);
        o.w = packbf(acc[6] * id, acc[7] * id);
        *(uint4*)&A[(size_t)node * HD + col * 8] = o;
    }
}

// ---------------- output GEMM (fp32 dot): out[n,c] = sum_k h[n,k]*W[c,k] + b[c] ----------------
__global__ __launch_bounds__(256) void out_gemm(const ushort* __restrict__ H,
                                                const float* __restrict__ W,
                                                const float* __restrict__ B,
                                                float* __restrict__ out) {
    __shared__ float wlds[NCLS * 132];
    __shared__ float xlds[6 * HD];
    int t = threadIdx.x;
    for (int j = t; j < NCLS * HD; j += 256) {
        int c = j >> 7, k = j & 127;
        wlds[c * 132 + k] = W[j];
    }
    __syncthreads();
    int r = t / NCLS, c = t % NCLS;
    bool act = t < 6 * NCLS;
    float bv = act ? B[c] : 0.f;
    const int NT = (NN + 5) / 6;
    for (int tile = blockIdx.x; tile < NT; tile += gridDim.x) {
        int r0 = tile * 6;
        __syncthreads();
        const unsigned int* hp = reinterpret_cast<const unsigned int*>(H + (size_t)r0 * HD);
        for (int j = t; j < 3 * HD; j += 256) {  // 384 uints = 768 bf16
            unsigned int v = hp[j];
            xlds[j * 2] = bflo(v);
            xlds[j * 2 + 1] = bfhi(v);
        }
        __syncthreads();
        if (!act) continue;
        int row = r0 + r;
        if (row < NN) {
            float acc = 0.f;
#pragma unroll
            for (int kk = 0; kk < HD; kk += 4) {
                float4 w = *reinterpret_cast<float4*>(&wlds[c * 132 + kk]);
                float4 xv = *reinterpret_cast<float4*>(&xlds[r * HD + kk]);
                acc += w.x * xv.x + w.y * xv.y + w.z * xv.z + w.w * xv.w;
            }
            out[(size_t)row * NCLS + c] = acc + bv;
        }
    }
}

extern "C" void kernel_launch(void* const* d_in, const int* in_sizes, int n_in,
                              void* d_out, int out_size, void* d_ws, size_t ws_size,
                              hipStream_t stream) {
    const float* x = (const float*)d_in[0];
    const void* ei = d_in[1];
    const float* fc0_w = (const float*)d_in[2];
    const float* bn_scale = (const float*)d_in[4];
    const float* bn_bias = (const float*)d_in[5];
    const float* lin_l = (const float*)d_in[6];
    const float* lin_r = (const float*)d_in[7];
    const float* W_w = (const float*)d_in[8];
    const float* out_w = (const float*)d_in[10];
    const float* out_b = (const float*)d_in[11];
    float* out = (float*)d_out;

    // ---- workspace carve-up (256B aligned) ----
    char* p = (char*)d_ws;
    auto alloc = [&](size_t bytes) -> void* {
        void* r = (void*)p;
        p += (bytes + 255) & ~(size_t)255;
        return r;
    };
    int* deg = (int*)alloc(NN * 4);
    int* cursor = (int*)alloc(NN * 4);
    int* eflag = (int*)alloc(256);
    size_t ctrl_bytes = (size_t)(p - (char*)d_ws);
    int* esrc = (int*)alloc(EE * 4);
    int* edst = (int*)alloc(EE * 4);
    int* rowptr = (int*)alloc((NN + 1) * 4);
    float* invdeg = (float*)alloc(NN * 4);
    int* adj = (int*)alloc(EE * 4);
    int* bsum = (int*)alloc(256 * 4);
    int* boff = (int*)alloc(256 * 4);
    float* parts = (float*)alloc((size_t)256 * GGRID * 4);  // stats partials [256][782]
    float* bnp = (float*)alloc(3 * 256 * 4);        // [3][scale128|bias128]
    ushort* Wcb = (ushort*)alloc(4 * HD * HD * 2);  // [layer][l/r][128][128] bf16
    ushort* wfc0 = (ushort*)alloc(HD * HD * 2);     // fc0_w bf16
    ushort* hpre = (ushort*)alloc((size_t)NN * HD * 2);  // pre-BN activations (bf16)
    ushort* hb = (ushort*)alloc((size_t)NN * HD * 2);
    ushort* aggb = (ushort*)alloc((size_t)NN * HD * 2);  // also reused as bf16 x

    hipMemsetAsync(d_ws, 0, ctrl_bytes, stream);

    // edge decode + degree
    detect_kernel<<<1, 256, 0, stream>>>(ei, eflag);
    decode_deg_kernel<<<1250, 512, 0, stream>>>(ei, eflag, esrc, edst, deg);

    // parallel scan -> rowptr/invdeg, then CSR fill
    deg_blocksum<<<196, 256, 0, stream>>>(deg, bsum);
    scan_bsums<<<1, 256, 0, stream>>>(bsum, boff);
    rowptr_fill<<<196, 256, 0, stream>>>(deg, boff, rowptr, invdeg);
    fill_kernel<<<1250, 512, 0, stream>>>(esrc, edst, rowptr, cursor, adj);

    // weights: combined (bf16) + fc0 (bf16); x -> bf16 (into aggb, free until layer0 agg)
    combine_w<<<dim3(HD, 4), HD, 0, stream>>>(W_w, lin_l, lin_r, Wcb);
    convw_kernel<<<64, 256, 0, stream>>>(fc0_w, wfc0);
    convx_kernel<<<3125, 256, 0, stream>>>(x, (ushort*)aggb);

    // fc0 + BN0 + ReLU (fc0_b dropped: cancelled by BN)
    gemm_mfma<false><<<GGRID, 256, 0, stream>>>((const ushort*)aggb, nullptr, wfc0, nullptr, hpre, parts);
    bn_fold2<<<128, 256, 0, stream>>>(parts, bn_scale, bn_bias, bnp);
    bn_relu<<<3125, 256, 0, stream>>>(hpre, bnp, hb);

    for (int layer = 0; layer < 2; ++layer) {
        agg_kernel<<<(NN + 3) / 4, 256, 0, stream>>>(hb, adj, rowptr, invdeg, aggb);
        const ushort* Wl = Wcb + (size_t)(layer * 2 + 0) * HD * HD;
        const ushort* Wr = Wcb + (size_t)(layer * 2 + 1) * HD * HD;
        // fused: hpre = bf16(aggb@Wl^T + hb@Wr^T) + stat partials (W_b cancelled by BN)
        gemm_mfma<true><<<GGRID, 256, 0, stream>>>(aggb, hb, Wl, Wr, hpre, parts);
        float* bp = bnp + (layer + 1) * 256;
        bn_fold2<<<128, 256, 0, stream>>>(parts, bn_scale + (layer + 1) * HD, bn_bias + (layer + 1) * HD, bp);
        bn_relu<<<3125, 256, 0, stream>>>(hpre, bp, hb);
    }

    out_gemm<<<512, 256, 0, stream>>>(hb, out_w, out_b, out);
}

// Round 10
// 229.429 us; speedup vs baseline: 3.3935x; 1.1885x over previous
//
#include <hip/hip_runtime.h>
#include <hip/hip_bf16.h>

#define NN 50000
#define EE 640000
#define HD 128
#define NCLS 40
#define BN_EPS 1e-5f
#define GTILES 1563  // ceil(NN/32)
#define GGRID 782    // gemm grid: each block does tiles {bid, bid+GGRID}
#define NB 98        // dst buckets of 512 nodes
#define ECHUNK 5000  // EE / 128

typedef short bf16x8 __attribute__((ext_vector_type(8)));
typedef float f32x4 __attribute__((ext_vector_type(4)));

__device__ __forceinline__ short f2bf(float f) {
    __hip_bfloat16 h = __float2bfloat16(f);
    return *reinterpret_cast<short*>(&h);
}
__device__ __forceinline__ float bflo(unsigned int v) { return __uint_as_float(v << 16); }
__device__ __forceinline__ float bfhi(unsigned int v) { return __uint_as_float(v & 0xffff0000u); }
__device__ __forceinline__ unsigned int packbf(float a, float b) {
    return (unsigned)(unsigned short)f2bf(a) | ((unsigned)(unsigned short)f2bf(b) << 16);
}

// ---------------- edge_index width detect ----------------
__global__ void detect_kernel(const void* __restrict__ ei, int* __restrict__ flag) {
    int t = threadIdx.x;  // 256
    const long long* p = (const long long*)ei;
    long long v = p[(size_t)t * (EE / 256)];
    if (v < 0 || v >= NN) atomicOr(flag, 1);  // flag=1 -> int32 data
}

// ---------------- degree + per-(block,bucket) histogram (reads ei directly) ----------------
__global__ __launch_bounds__(512) void deg_hist(const void* __restrict__ ei,
                                                const int* __restrict__ flag,
                                                int* __restrict__ deg, int* __restrict__ cnt) {
    __shared__ int lh[NB];
    int t = threadIdx.x, b = blockIdx.x;
    if (t < NB) lh[t] = 0;
    __syncthreads();
    bool narrow = (*flag != 0);
    int e0 = b * ECHUNK;
    for (int e = e0 + t; e < e0 + ECHUNK; e += 512) {
        int d = narrow ? ((const int*)ei)[EE + e] : (int)((const long long*)ei)[EE + e];
        atomicAdd(&deg[d], 1);
        atomicAdd(&lh[d >> 9], 1);
    }
    __syncthreads();
    if (t < NB) cnt[b * NB + t] = lh[t];
}

// ---------------- parallel scan: deg -> rowptr, invdeg ----------------
__global__ void deg_blocksum(const int* __restrict__ deg, int* __restrict__ bsum) {
    int i = blockIdx.x * 256 + threadIdx.x;
    int d = (i < NN) ? deg[i] : 0;
#pragma unroll
    for (int o = 32; o; o >>= 1) d += __shfl_down(d, o);
    __shared__ int ws[4];
    if ((threadIdx.x & 63) == 0) ws[threadIdx.x >> 6] = d;
    __syncthreads();
    if (threadIdx.x == 0) bsum[blockIdx.x] = ws[0] + ws[1] + ws[2] + ws[3];
}

__global__ void scan_bsums(const int* __restrict__ bsum, int* __restrict__ boff) {
    __shared__ int s[256];
    int t = threadIdx.x;
    int v = (t < 196) ? bsum[t] : 0;
    s[t] = v;
    __syncthreads();
    for (int o = 1; o < 256; o <<= 1) {
        int u = (t >= o) ? s[t - o] : 0;
        __syncthreads();
        s[t] += u;
        __syncthreads();
    }
    if (t < 196) boff[t] = s[t] - v;  // exclusive
}

__global__ void rowptr_fill(const int* __restrict__ deg, const int* __restrict__ boff,
                            int* __restrict__ rowptr, float* __restrict__ invdeg) {
    int b = blockIdx.x, t = threadIdx.x, i = b * 256 + t;
    int d = (i < NN) ? deg[i] : 0;
    __shared__ int s[256];
    s[t] = d;
    __syncthreads();
    for (int o = 1; o < 256; o <<= 1) {
        int u = (t >= o) ? s[t - o] : 0;
        __syncthreads();
        s[t] += u;
        __syncthreads();
    }
    int excl = s[t] - d + boff[b];
    if (i < NN) {
        rowptr[i] = excl;
        invdeg[i] = 1.0f / (float)(d > 1 ? d : 1);
        if (i == NN - 1) rowptr[NN] = excl + d;
    }
}

// ---------------- per-(block,bucket) offsets: O[b][k] = rowptr[k*512] + prefix of cnt ----
__global__ void bucket_off(const int* __restrict__ cnt, const int* __restrict__ rowptr,
                           int* __restrict__ boffs) {
    int k = threadIdx.x;  // 128 threads, NB active
    if (k >= NB) return;
    int run = rowptr[k << 9];
    for (int b = 0; b < 128; ++b) {
        boffs[b * NB + k] = run;
        run += cnt[b * NB + k];
    }
}

// ---------------- scatter edges into block-private bucket regions (dense writes) ----------
__global__ __launch_bounds__(512) void bucket_scatter(const void* __restrict__ ei,
                                                      const int* __restrict__ flag,
                                                      const int* __restrict__ boffs,
                                                      uint2* __restrict__ bkt) {
    __shared__ int lc[NB];
    int t = threadIdx.x, b = blockIdx.x;
    if (t < NB) lc[t] = boffs[b * NB + t];
    __syncthreads();
    bool narrow = (*flag != 0);
    int e0 = b * ECHUNK;
    for (int e = e0 + t; e < e0 + ECHUNK; e += 512) {
        int s, d;
        if (narrow) {
            s = ((const int*)ei)[e];
            d = ((const int*)ei)[EE + e];
        } else {
            s = (int)((const long long*)ei)[e];
            d = (int)((const long long*)ei)[EE + e];
        }
        int pos = atomicAdd(&lc[d >> 9], 1);
        bkt[pos] = make_uint2((unsigned)s, (unsigned)d);
    }
}

// ---------------- per-bucket final CSR build: LDS adj image, coalesced write ------------
__global__ __launch_bounds__(512) void bucket_build(const uint2* __restrict__ bkt,
                                                    const int* __restrict__ rowptr,
                                                    int* __restrict__ adj) {
    __shared__ int lcur[512];
    __shared__ int ladj[8192];
    int t = threadIdx.x, k = blockIdx.x;
    int nodeBase = k << 9;
    int nn = NN - nodeBase;
    if (nn > 512) nn = 512;
    int e0 = rowptr[nodeBase], e1 = rowptr[nodeBase + nn];
    if (t < nn) lcur[t] = rowptr[nodeBase + t] - e0;
    int ne = e1 - e0;
    __syncthreads();
    if (ne <= 8192) {
        for (int i = e0 + t; i < e1; i += 512) {
            uint2 p = bkt[i];
            int pos = atomicAdd(&lcur[(int)p.y - nodeBase], 1);
            ladj[pos] = (int)p.x;
        }
        __syncthreads();
        for (int i = t; i < ne; i += 512) adj[e0 + i] = ladj[i];
    } else {  // overflow fallback (never for this graph; correctness net)
        for (int i = e0 + t; i < e1; i += 512) {
            uint2 p = bkt[i];
            int pos = atomicAdd(&lcur[(int)p.y - nodeBase], 1);
            adj[e0 + pos] = (int)p.x;
        }
    }
}

// ---------------- weights: Wc[which] = bf16(W_w @ lin_{l/r}[layer]); fc0/out -> bf16 -----
__global__ void combine_w(const float* __restrict__ Ww, const float* __restrict__ linl,
                          const float* __restrict__ linr, ushort* __restrict__ Wcb) {
    int k = threadIdx.x;
    int m = blockIdx.x;
    int which = blockIdx.y;  // layer = which>>1, l/r = which&1
    const float* lin = ((which & 1) ? linr : linl) + (which >> 1) * HD * HD;
    __shared__ float wrow[HD];
    wrow[k] = Ww[m * HD + k];
    __syncthreads();
    float acc = 0.f;
    for (int j = 0; j < HD; ++j) acc += wrow[j] * lin[j * HD + k];
    Wcb[which * HD * HD + m * HD + k] = (unsigned short)f2bf(acc);
}

__global__ void convw_kernel(const float* __restrict__ W, ushort* __restrict__ Wb) {
    int i = blockIdx.x * 256 + threadIdx.x;
    if (i < HD * HD) Wb[i] = (unsigned short)f2bf(W[i]);
}

// out_w [40][128] -> bf16 [48][128] zero-padded
__global__ void convw48(const float* __restrict__ W, ushort* __restrict__ Wb) {
    int i = blockIdx.x * 256 + threadIdx.x;
    if (i < 48 * HD) Wb[i] = (i < NCLS * HD) ? (unsigned short)f2bf(W[i]) : (unsigned short)0;
}

// ---------------- MFMA GEMM v6: LDS-staged, pipelined, fused stat partials --------------
// Y = bf16( A1@W1^T (+ A2@W2^T) ); A1 fp32 (F32A, packed to bf16 in-reg) or bf16.
// Per-column sum/sqsum partials from the fp32 accumulator -> parts[col][bid] (no atomics).
template <bool DUAL, bool F32A>
__global__ __launch_bounds__(256) void gemm_mfma(const void* __restrict__ A1v,
                                                 const ushort* __restrict__ A2g,
                                                 const ushort* __restrict__ W1,
                                                 const ushort* __restrict__ W2,
                                                 ushort* __restrict__ Y,
                                                 float* __restrict__ parts) {
    __shared__ __align__(16) char lds[32768];
    const int t = threadIdx.x;
    const int l = t & 63, w = t >> 6;
    const int lr = l & 15, lg = l >> 4;
    constexpr int BUFSZ = DUAL ? 16384 : 8192;

    // ---- weight setup: stage 32KB coalesced into LDS, extract frags to regs ----
    bf16x8 bw1[2][4], bw2[2][4];
    {
        const uint4* srcw = (const uint4*)W1;
        for (int i = t; i < 2048; i += 256) ((uint4*)lds)[i] = srcw[i];
        __syncthreads();
#pragma unroll
        for (int cc = 0; cc < 2; ++cc)
#pragma unroll
            for (int kk = 0; kk < 4; ++kk)
                bw1[cc][kk] = *(const bf16x8*)&lds[((w * 2 + cc) * 16 + lr) * 256 + kk * 64 + lg * 16];
        if constexpr (DUAL) {
            __syncthreads();
            const uint4* srcw2 = (const uint4*)W2;
            for (int i = t; i < 2048; i += 256) ((uint4*)lds)[i] = srcw2[i];
            __syncthreads();
#pragma unroll
            for (int cc = 0; cc < 2; ++cc)
#pragma unroll
                for (int kk = 0; kk < 4; ++kk)
                    bw2[cc][kk] = *(const bf16x8*)&lds[((w * 2 + cc) * 16 + lr) * 256 + kk * 64 + lg * 16];
        }
        __syncthreads();
    }

    const int t0 = blockIdx.x;
    const int t1 = blockIdx.x + GGRID;
    const bool has2 = (t1 < GTILES);

    f32x4 ss[2] = {}, sq[2] = {};

    uint4 st1[2], st2[2], fx[4];
    auto stage_load = [&](int tile) {
#pragma unroll
        for (int s = 0; s < 2; ++s) {
            int o = s * 4096 + t * 16;           // linear dest byte in bf16 A-region
            int po = o ^ (((o >> 8) & 7) << 4);  // pre-swizzled source byte
            int grow = tile * 32 + (po >> 8);
            if (grow > NN - 1) grow = NN - 1;
            if constexpr (F32A) {
                const char* src = (const char*)A1v + (size_t)grow * 512 + (size_t)(po & 255) * 2;
                fx[s * 2] = *(const uint4*)src;
                fx[s * 2 + 1] = *(const uint4*)(src + 16);
            } else {
                st1[s] = *(const uint4*)((const char*)A1v + (size_t)grow * 256 + (po & 255));
            }
            if constexpr (DUAL)
                st2[s] = *(const uint4*)((const char*)A2g + (size_t)grow * 256 + (po & 255));
        }
    };
    auto stage_write = [&](int buf) {
        char* base = lds + buf * BUFSZ;
#pragma unroll
        for (int s = 0; s < 2; ++s) {
            uint4 v;
            if constexpr (F32A) {
                uint4 a = fx[s * 2], b2 = fx[s * 2 + 1];
                v.x = packbf(__uint_as_float(a.x), __uint_as_float(a.y));
                v.y = packbf(__uint_as_float(a.z), __uint_as_float(a.w));
                v.z = packbf(__uint_as_float(b2.x), __uint_as_float(b2.y));
                v.w = packbf(__uint_as_float(b2.z), __uint_as_float(b2.w));
            } else {
                v = st1[s];
            }
            *(uint4*)(base + s * 4096 + t * 16) = v;
            if constexpr (DUAL) *(uint4*)(base + 8192 + s * 4096 + t * 16) = st2[s];
        }
    };
    auto compute = [&](int tile, int buf) {
        const char* base = lds + buf * BUFSZ;
        f32x4 acc[2][2] = {};
#pragma unroll
        for (int rf = 0; rf < 2; ++rf) {
            int rowb = (rf * 16 + lr) * 256;
            int sw = (lr & 7) << 4;
            bf16x8 a1[4], a2[4];
#pragma unroll
            for (int kk = 0; kk < 4; ++kk) {
                int q = rowb + ((kk * 64 + lg * 16) ^ sw);
                a1[kk] = *(const bf16x8*)(base + q);
                if constexpr (DUAL) a2[kk] = *(const bf16x8*)(base + 8192 + q);
            }
#pragma unroll
            for (int kk = 0; kk < 4; ++kk)
#pragma unroll
                for (int cc = 0; cc < 2; ++cc) {
                    acc[rf][cc] = __builtin_amdgcn_mfma_f32_16x16x32_bf16(bw1[cc][kk], a1[kk], acc[rf][cc], 0, 0, 0);
                    if constexpr (DUAL)
                        acc[rf][cc] = __builtin_amdgcn_mfma_f32_16x16x32_bf16(bw2[cc][kk], a2[kk], acc[rf][cc], 0, 0, 0);
                }
        }
#pragma unroll
        for (int rf = 0; rf < 2; ++rf) {
            int row = tile * 32 + rf * 16 + lr;
            if (row < NN) {
#pragma unroll
                for (int cc = 0; cc < 2; ++cc) {
                    f32x4 v = acc[rf][cc];
                    uint2 o;
                    o.x = packbf(v[0], v[1]);
                    o.y = packbf(v[2], v[3]);
                    *(uint2*)&Y[(size_t)row * HD + (w * 2 + cc) * 16 + lg * 4] = o;
                    ss[cc] += v;
                    sq[cc] += v * v;
                }
            }
        }
    };

    // ---- pipeline: stage t0; issue t1 loads; compute t0 (t1 in flight); write t1; compute ----
    stage_load(t0);
    stage_write(0);
    if (has2) stage_load(t1);  // in flight during compute(t0)
    __syncthreads();
    compute(t0, 0);
    if (has2) {
        stage_write(1);
        __syncthreads();
        compute(t1, 1);
    }

    // ---- stat partials: reduce over the 16 lr lanes (rows), write parts[col][bid] ----
#pragma unroll
    for (int cc = 0; cc < 2; ++cc)
#pragma unroll
        for (int j = 0; j < 4; ++j) {
            float a = ss[cc][j], b = sq[cc][j];
#pragma unroll
            for (int m = 1; m < 16; m <<= 1) {
                a += __shfl_xor(a, m);
                b += __shfl_xor(b, m);
            }
            if (lr == 0) {
                int col = (w * 2 + cc) * 16 + lg * 4 + j;
                parts[(size_t)col * GGRID + blockIdx.x] = a;
                parts[(size_t)(HD + col) * GGRID + blockIdx.x] = b;
            }
        }
}

// ---------------- BN fold v2: block j reduces 782 partials for col j -> bnp ----------------
__global__ __launch_bounds__(256) void bn_fold2(const float* __restrict__ parts,
                                                const float* __restrict__ scale,
                                                const float* __restrict__ bias,
                                                float* __restrict__ bnp) {
    __shared__ float r1[256], r2[256];
    int j = blockIdx.x;   // 0..127 column
    int t = threadIdx.x;  // 256
    float a = 0.f, b = 0.f;
    for (int i = t; i < GGRID; i += 256) {
        a += parts[(size_t)j * GGRID + i];
        b += parts[(size_t)(HD + j) * GGRID + i];
    }
    r1[t] = a; r2[t] = b;
    __syncthreads();
    for (int o = 128; o; o >>= 1) {
        if (t < o) { r1[t] += r1[t + o]; r2[t] += r2[t + o]; }
        __syncthreads();
    }
    if (t == 0) {
        float mu = r1[0] * (1.0f / NN);
        float var = r2[0] * (1.0f / NN) - mu * mu;
        float sc = scale[j] * rsqrtf(var + BN_EPS);
        bnp[j] = sc;
        bnp[HD + j] = bias[j] - mu * sc;
    }
}

__global__ __launch_bounds__(256) void bn_relu(const ushort* __restrict__ Hp,
                                               const float* __restrict__ bnp,
                                               ushort* __restrict__ Hb) {
    int i = blockIdx.x * 256 + threadIdx.x;  // one thread per 8 features
    if (i >= NN * HD / 8) return;
    int mb = (i & 15) * 8;
    uint4 v = reinterpret_cast<const uint4*>(Hp)[i];
    float4 sa = *reinterpret_cast<const float4*>(&bnp[mb]);
    float4 sb = *reinterpret_cast<const float4*>(&bnp[mb + 4]);
    float4 ba = *reinterpret_cast<const float4*>(&bnp[HD + mb]);
    float4 bb = *reinterpret_cast<const float4*>(&bnp[HD + mb + 4]);
    float v0 = fmaxf(bflo(v.x) * sa.x + ba.x, 0.f);
    float v1 = fmaxf(bfhi(v.x) * sa.y + ba.y, 0.f);
    float v2 = fmaxf(bflo(v.y) * sa.z + ba.z, 0.f);
    float v3 = fmaxf(bfhi(v.y) * sa.w + ba.w, 0.f);
    float v4 = fmaxf(bflo(v.z) * sb.x + bb.x, 0.f);
    float v5 = fmaxf(bfhi(v.z) * sb.y + bb.y, 0.f);
    float v6 = fmaxf(bflo(v.w) * sb.z + bb.z, 0.f);
    float v7 = fmaxf(bfhi(v.w) * sb.w + bb.w, 0.f);
    uint4 o;
    o.x = packbf(v0, v1);
    o.y = packbf(v2, v3);
    o.z = packbf(v4, v5);
    o.w = packbf(v6, v7);
    *reinterpret_cast<uint4*>(Hb + (size_t)i * 8) = o;
}

// ---------------- aggregation v2: 8 neighbors in flight per wave-iteration ----------------
__global__ __launch_bounds__(256) void agg_kernel(const ushort* __restrict__ H,
                                                  const int* __restrict__ adj,
                                                  const int* __restrict__ rowptr,
                                                  const float* __restrict__ invdeg,
                                                  ushort* __restrict__ A) {
    int node = blockIdx.x * 4 + (threadIdx.x >> 6);
    if (node >= NN) return;
    int l = threadIdx.x & 63;
    int slot = l >> 4, col = l & 15;
    int b = rowptr[node], e = rowptr[node + 1];
    float id = invdeg[node];
    float acc[8] = {};
    for (int i = b; i < e; i += 8) {
        int i0 = i + slot, i1 = i + 4 + slot;
        bool v0 = i0 < e, v1 = i1 < e;
        int s0 = adj[v0 ? i0 : i];
        int s1 = adj[v1 ? i1 : i];
        uint4 a = *(const uint4*)&H[(size_t)s0 * HD + col * 8];
        uint4 c = *(const uint4*)&H[(size_t)s1 * HD + col * 8];
        float m0 = v0 ? 1.f : 0.f, m1 = v1 ? 1.f : 0.f;
        acc[0] += bflo(a.x) * m0 + bflo(c.x) * m1;
        acc[1] += bfhi(a.x) * m0 + bfhi(c.x) * m1;
        acc[2] += bflo(a.y) * m0 + bflo(c.y) * m1;
        acc[3] += bfhi(a.y) * m0 + bfhi(c.y) * m1;
        acc[4] += bflo(a.z) * m0 + bflo(c.z) * m1;
        acc[5] += bfhi(a.z) * m0 + bfhi(c.z) * m1;
        acc[6] += bflo(a.w) * m0 + bflo(c.w) * m1;
        acc[7] += bfhi(a.w) * m0 + bfhi(c.w) * m1;
    }
#pragma unroll
    for (int c2 = 0; c2 < 8; ++c2) {
        acc[c2] += __shfl_xor(acc[c2], 16);
        acc[c2] += __shfl_xor(acc[c2], 32);
    }
    if (slot == 0) {
        uint4 o;
        o.x = packbf(acc[0] * id, acc[1] * id);
        o.y = packbf(acc[2] * id, acc[3] * id);
        o.z = packbf(acc[4] * id, acc[5] * id);
        o.w = packbf(acc[6] * id, acc[7] * id);
        *(uint4*)&A[(size_t)node * HD + col * 8] = o;
    }
}

// ---------------- output: MFMA, out[n,c] = sum_k h[n,k]*W48[c,k] + b[c], fp32 out -------
__global__ __launch_bounds__(256) void out_mfma(const ushort* __restrict__ Hb,
                                                const ushort* __restrict__ W48,
                                                const float* __restrict__ B,
                                                float* __restrict__ out) {
    __shared__ __align__(16) char lds[16384];
    __shared__ float blds[48];
    const int t = threadIdx.x;
    const int l = t & 63;
    const int lr = l & 15, lg = l >> 4;
    if (t < 48) blds[t] = (t < NCLS) ? B[t] : 0.f;

    bf16x8 bw[3][4];
#pragma unroll
    for (int cc = 0; cc < 3; ++cc)
#pragma unroll
        for (int kk = 0; kk < 4; ++kk)
            bw[cc][kk] = *(const bf16x8*)&W48[(size_t)(cc * 16 + lr) * HD + kk * 32 + lg * 8];

    const int t0 = blockIdx.x, t1 = blockIdx.x + GGRID;
    const bool has2 = (t1 < GTILES);

    uint4 s1a[2];
    auto stage_load = [&](int tile) {
#pragma unroll
        for (int s = 0; s < 2; ++s) {
            int o = s * 4096 + t * 16;
            int po = o ^ (((o >> 8) & 7) << 4);
            int grow = tile * 32 + (po >> 8);
            if (grow > NN - 1) grow = NN - 1;
            s1a[s] = *(const uint4*)((const char*)Hb + (size_t)grow * 256 + (po & 255));
        }
    };
    auto stage_write = [&](int buf) {
        char* base = lds + buf * 8192;
#pragma unroll
        for (int s = 0; s < 2; ++s) *(uint4*)(base + s * 4096 + t * 16) = s1a[s];
    };
    auto compute = [&](int tile, int buf) {
        const char* base = lds + buf * 8192;
        f32x4 acc[2][3] = {};
#pragma unroll
        for (int rf = 0; rf < 2; ++rf) {
            int rowb = (rf * 16 + lr) * 256;
            int sw = (lr & 7) << 4;
            bf16x8 a1[4];
#pragma unroll
            for (int kk = 0; kk < 4; ++kk)
                a1[kk] = *(const bf16x8*)(base + rowb + ((kk * 64 + lg * 16) ^ sw));
#pragma unroll
            for (int kk = 0; kk < 4; ++kk)
#pragma unroll
                for (int cc = 0; cc < 3; ++cc)
                    acc[rf][cc] = __builtin_amdgcn_mfma_f32_16x16x32_bf16(bw[cc][kk], a1[kk], acc[rf][cc], 0, 0, 0);
        }
#pragma unroll
        for (int rf = 0; rf < 2; ++rf) {
            int row = tile * 32 + rf * 16 + lr;
            if (row < NN) {
#pragma unroll
                for (int cc = 0; cc < 3; ++cc) {
                    int col = cc * 16 + lg * 4;
                    if (col < NCLS) {
                        float4 bv = *(const float4*)&blds[col];
                        float2 lo = {acc[rf][cc][0] + bv.x, acc[rf][cc][1] + bv.y};
                        float2 hi = {acc[rf][cc][2] + bv.z, acc[rf][cc][3] + bv.w};
                        *(float2*)&out[(size_t)row * NCLS + col] = lo;
                        *(float2*)&out[(size_t)row * NCLS + col + 2] = hi;
                    }
                }
            }
        }
    };

    stage_load(t0);
    stage_write(0);
    if (has2) stage_load(t1);
    __syncthreads();
    compute(t0, 0);
    if (has2) {
        stage_write(1);
        __syncthreads();
        compute(t1, 1);
    }
}

extern "C" void kernel_launch(void* const* d_in, const int* in_sizes, int n_in,
                              void* d_out, int out_size, void* d_ws, size_t ws_size,
                              hipStream_t stream) {
    const float* x = (const float*)d_in[0];
    const void* ei = d_in[1];
    const float* fc0_w = (const float*)d_in[2];
    const float* bn_scale = (const float*)d_in[4];
    const float* bn_bias = (const float*)d_in[5];
    const float* lin_l = (const float*)d_in[6];
    const float* lin_r = (const float*)d_in[7];
    const float* W_w = (const float*)d_in[8];
    const float* out_w = (const float*)d_in[10];
    const float* out_b = (const float*)d_in[11];
    float* out = (float*)d_out;

    // ---- workspace carve-up (256B aligned) ----
    char* p = (char*)d_ws;
    auto alloc = [&](size_t bytes) -> void* {
        void* r = (void*)p;
        p += (bytes + 255) & ~(size_t)255;
        return r;
    };
    int* deg = (int*)alloc(NN * 4);
    int* eflag = (int*)alloc(256);
    size_t ctrl_bytes = (size_t)(p - (char*)d_ws);
    int* rowptr = (int*)alloc((NN + 1) * 4);
    float* invdeg = (float*)alloc(NN * 4);
    int* adj = (int*)alloc(EE * 4);
    int* bsum = (int*)alloc(256 * 4);
    int* boff = (int*)alloc(256 * 4);
    int* cnt = (int*)alloc(128 * NB * 4);
    int* boffs = (int*)alloc(128 * NB * 4);
    uint2* bkt = (uint2*)alloc((size_t)EE * 8);
    float* parts = (float*)alloc((size_t)256 * GGRID * 4);  // stats partials [256][782]
    float* bnp = (float*)alloc(3 * 256 * 4);        // [3][scale128|bias128]
    ushort* Wcb = (ushort*)alloc(4 * HD * HD * 2);  // [layer][l/r][128][128] bf16
    ushort* wfc0 = (ushort*)alloc(HD * HD * 2);     // fc0_w bf16
    ushort* wo48 = (ushort*)alloc(48 * HD * 2);     // out_w bf16 zero-padded to 48 rows
    ushort* hpre = (ushort*)alloc((size_t)NN * HD * 2);  // pre-BN activations (bf16)
    ushort* hb = (ushort*)alloc((size_t)NN * HD * 2);
    ushort* aggb = (ushort*)alloc((size_t)NN * HD * 2);

    hipMemsetAsync(d_ws, 0, ctrl_bytes, stream);

    // graph build: detect -> deg+hist -> scan -> rowptr -> bucket offsets -> scatter -> build
    detect_kernel<<<1, 256, 0, stream>>>(ei, eflag);
    deg_hist<<<128, 512, 0, stream>>>(ei, eflag, deg, cnt);
    deg_blocksum<<<196, 256, 0, stream>>>(deg, bsum);
    scan_bsums<<<1, 256, 0, stream>>>(bsum, boff);
    rowptr_fill<<<196, 256, 0, stream>>>(deg, boff, rowptr, invdeg);
    bucket_off<<<1, 128, 0, stream>>>(cnt, rowptr, boffs);
    bucket_scatter<<<128, 512, 0, stream>>>(ei, eflag, boffs, bkt);
    bucket_build<<<NB, 512, 0, stream>>>(bkt, rowptr, adj);

    // weights
    combine_w<<<dim3(HD, 4), HD, 0, stream>>>(W_w, lin_l, lin_r, Wcb);
    convw_kernel<<<64, 256, 0, stream>>>(fc0_w, wfc0);
    convw48<<<24, 256, 0, stream>>>(out_w, wo48);

    // fc0 (reads fp32 x directly) + BN0 + ReLU (fc0_b dropped: cancelled by BN)
    gemm_mfma<false, true><<<GGRID, 256, 0, stream>>>(x, nullptr, wfc0, nullptr, hpre, parts);
    bn_fold2<<<128, 256, 0, stream>>>(parts, bn_scale, bn_bias, bnp);
    bn_relu<<<3125, 256, 0, stream>>>(hpre, bnp, hb);

    for (int layer = 0; layer < 2; ++layer) {
        agg_kernel<<<(NN + 3) / 4, 256, 0, stream>>>(hb, adj, rowptr, invdeg, aggb);
        const ushort* Wl = Wcb + (size_t)(layer * 2 + 0) * HD * HD;
        const ushort* Wr = Wcb + (size_t)(layer * 2 + 1) * HD * HD;
        // fused: hpre = bf16(aggb@Wl^T + hb@Wr^T) + stat partials (W_b cancelled by BN)
        gemm_mfma<true, false><<<GGRID, 256, 0, stream>>>(aggb, hb, Wl, Wr, hpre, parts);
        float* bp = bnp + (layer + 1) * 256;
        bn_fold2<<<128, 256, 0, stream>>>(parts, bn_scale + (layer + 1) * HD, bn_bias + (layer + 1) * HD, bp);
        bn_relu<<<3125, 256, 0, stream>>>(hpre, bp, hb);
    }

    out_mfma<<<GGRID, 256, 0, stream>>>(hb, wo48, out_b, out);
}

// Round 11
// 181.129 us; speedup vs baseline: 4.2984x; 1.2667x over previous
//
#include <hip/hip_runtime.h>
#include <hip/hip_bf16.h>

#define NN 50000
#define EE 640000
#define HD 128
#define NCLS 40
#define BN_EPS 1e-5f
#define GTILES 1563  // ceil(NN/32)
#define GGRID 782    // gemm grid: each block does tiles {bid, bid+GGRID}
#define NB 98        // dst buckets of 512 nodes
#define ECHUNK 5000  // EE / 128

typedef short bf16x8 __attribute__((ext_vector_type(8)));
typedef float f32x4 __attribute__((ext_vector_type(4)));

__device__ __forceinline__ short f2bf(float f) {
    __hip_bfloat16 h = __float2bfloat16(f);
    return *reinterpret_cast<short*>(&h);
}
__device__ __forceinline__ float bflo(unsigned int v) { return __uint_as_float(v << 16); }
__device__ __forceinline__ float bfhi(unsigned int v) { return __uint_as_float(v & 0xffff0000u); }
__device__ __forceinline__ unsigned int packbf(float a, float b) {
    return (unsigned)(unsigned short)f2bf(a) | ((unsigned)(unsigned short)f2bf(b) << 16);
}

// ---------------- edge_index width detect ----------------
__global__ void detect_kernel(const void* __restrict__ ei, int* __restrict__ flag) {
    int t = threadIdx.x;  // 256
    const long long* p = (const long long*)ei;
    long long v = p[(size_t)t * (EE / 256)];
    if (v < 0 || v >= NN) atomicOr(flag, 1);  // flag=1 -> int32 data
}

// ---------------- per-(block,bucket) histogram (LDS only, no global atomics) ----------------
__global__ __launch_bounds__(512) void hist_kernel(const void* __restrict__ ei,
                                                   const int* __restrict__ flag,
                                                   int* __restrict__ cnt) {
    __shared__ int lh[NB];
    int t = threadIdx.x, b = blockIdx.x;
    if (t < NB) lh[t] = 0;
    __syncthreads();
    bool narrow = (*flag != 0);
    int e0 = b * ECHUNK;
    for (int e = e0 + t; e < e0 + ECHUNK; e += 512) {
        int d = narrow ? ((const int*)ei)[EE + e] : (int)((const long long*)ei)[EE + e];
        atomicAdd(&lh[d >> 9], 1);
    }
    __syncthreads();
    if (t < NB) cnt[b * NB + t] = lh[t];
}

// ---------------- bucket bases + per-(block,bucket) scatter offsets ----------------
__global__ void bucket_off2(const int* __restrict__ cnt, int* __restrict__ boffs,
                            int* __restrict__ ebase) {
    __shared__ int s[128];
    int k = threadIdx.x;  // 0..127, NB active
    int tot = 0;
    if (k < NB)
        for (int b = 0; b < 128; ++b) tot += cnt[b * NB + k];
    s[k] = tot;
    __syncthreads();
    for (int o = 1; o < 128; o <<= 1) {
        int u = (k >= o) ? s[k - o] : 0;
        __syncthreads();
        s[k] += u;
        __syncthreads();
    }
    if (k < NB) {
        int base = s[k] - tot;  // exclusive
        ebase[k] = base;
        if (k == NB - 1) ebase[NB] = base + tot;  // = EE
        int run = base;
        for (int b = 0; b < 128; ++b) {
            boffs[b * NB + k] = run;
            run += cnt[b * NB + k];
        }
    }
}

// ---------------- scatter edges into block-private bucket regions (dense writes) ----------
__global__ __launch_bounds__(512) void bucket_scatter(const void* __restrict__ ei,
                                                      const int* __restrict__ flag,
                                                      const int* __restrict__ boffs,
                                                      uint2* __restrict__ bkt) {
    __shared__ int lc[NB];
    int t = threadIdx.x, b = blockIdx.x;
    if (t < NB) lc[t] = boffs[b * NB + t];
    __syncthreads();
    bool narrow = (*flag != 0);
    int e0 = b * ECHUNK;
    for (int e = e0 + t; e < e0 + ECHUNK; e += 512) {
        int s, d;
        if (narrow) {
            s = ((const int*)ei)[e];
            d = ((const int*)ei)[EE + e];
        } else {
            s = (int)((const long long*)ei)[e];
            d = (int)((const long long*)ei)[EE + e];
        }
        int pos = atomicAdd(&lc[d >> 9], 1);
        bkt[pos] = make_uint2((unsigned)s, (unsigned)d);
    }
}

// ---------------- per-bucket CSR build: LDS degree+scan+adj image, coalesced out --------
__global__ __launch_bounds__(512) void bucket_build(const uint2* __restrict__ bkt,
                                                    const int* __restrict__ ebase,
                                                    int* __restrict__ rowptr,
                                                    float* __restrict__ invdeg,
                                                    int* __restrict__ adj) {
    __shared__ int ldeg[512];
    __shared__ int lcur[512];
    __shared__ int ladj[8192];
    int t = threadIdx.x, k = blockIdx.x;
    int nodeBase = k << 9;
    int nn = NN - nodeBase;
    if (nn > 512) nn = 512;
    int e0 = ebase[k], e1 = ebase[k + 1];
    int ne = e1 - e0;
    ldeg[t] = 0;
    __syncthreads();
    for (int i = e0 + t; i < e1; i += 512)
        atomicAdd(&ldeg[(int)bkt[i].y - nodeBase], 1);
    __syncthreads();
    int d = ldeg[t];
    lcur[t] = d;
    __syncthreads();
    for (int o = 1; o < 512; o <<= 1) {  // inclusive scan
        int u = (t >= o) ? lcur[t - o] : 0;
        __syncthreads();
        lcur[t] += u;
        __syncthreads();
    }
    int excl = lcur[t] - d;
    if (t < nn) {
        rowptr[nodeBase + t] = e0 + excl;
        invdeg[nodeBase + t] = 1.0f / (float)(d > 1 ? d : 1);
    }
    if (k == 0 && t == 0) rowptr[NN] = EE;
    __syncthreads();
    lcur[t] = excl;  // reuse as cursor
    __syncthreads();
    if (ne <= 8192) {
        for (int i = e0 + t; i < e1; i += 512) {
            uint2 p = bkt[i];
            int pos = atomicAdd(&lcur[(int)p.y - nodeBase], 1);
            ladj[pos] = (int)p.x;
        }
        __syncthreads();
        for (int i = t; i < ne; i += 512) adj[e0 + i] = ladj[i];
    } else {  // overflow fallback (never for this graph; correctness net)
        for (int i = e0 + t; i < e1; i += 512) {
            uint2 p = bkt[i];
            int pos = atomicAdd(&lcur[(int)p.y - nodeBase], 1);
            adj[e0 + pos] = (int)p.x;
        }
    }
}

// ---------------- weights: Wc[which] = bf16(W_w @ lin_{l/r}[layer]); fc0/out -> bf16 -----
__global__ void combine_w(const float* __restrict__ Ww, const float* __restrict__ linl,
                          const float* __restrict__ linr, ushort* __restrict__ Wcb) {
    int k = threadIdx.x;
    int m = blockIdx.x;
    int which = blockIdx.y;  // layer = which>>1, l/r = which&1
    const float* lin = ((which & 1) ? linr : linl) + (which >> 1) * HD * HD;
    __shared__ float wrow[HD];
    wrow[k] = Ww[m * HD + k];
    __syncthreads();
    float acc = 0.f;
    for (int j = 0; j < HD; ++j) acc += wrow[j] * lin[j * HD + k];
    Wcb[which * HD * HD + m * HD + k] = (unsigned short)f2bf(acc);
}

__global__ void convw_kernel(const float* __restrict__ W, ushort* __restrict__ Wb) {
    int i = blockIdx.x * 256 + threadIdx.x;
    if (i < HD * HD) Wb[i] = (unsigned short)f2bf(W[i]);
}

// out_w [40][128] -> bf16 [48][128] zero-padded
__global__ void convw48(const float* __restrict__ W, ushort* __restrict__ Wb) {
    int i = blockIdx.x * 256 + threadIdx.x;
    if (i < 48 * HD) Wb[i] = (i < NCLS * HD) ? (unsigned short)f2bf(W[i]) : (unsigned short)0;
}

// ---------------- MFMA GEMM v7: LDS-staged, pipelined, fused stats + fused BN on A2 -----
// Y = bf16( A1@W1^T (+ relu(bn(A2))@W2^T) ); A1 fp32 (F32A) or bf16.
// A2 is PRE-BN bf16; bnp (scale[128]|bias[128]) applied during LDS stage_write.
// Per-column sum/sqsum partials from the fp32 accumulator -> parts[col][bid] (no atomics).
template <bool DUAL, bool F32A>
__global__ __launch_bounds__(256) void gemm_mfma(const void* __restrict__ A1v,
                                                 const ushort* __restrict__ A2g,
                                                 const float* __restrict__ bnp,
                                                 const ushort* __restrict__ W1,
                                                 const ushort* __restrict__ W2,
                                                 ushort* __restrict__ Y,
                                                 float* __restrict__ parts) {
    __shared__ __align__(16) char lds[32768];
    const int t = threadIdx.x;
    const int l = t & 63, w = t >> 6;
    const int lr = l & 15, lg = l >> 4;
    constexpr int BUFSZ = DUAL ? 16384 : 8192;

    // ---- weight setup: stage 32KB coalesced into LDS, extract frags to regs ----
    bf16x8 bw1[2][4], bw2[2][4];
    {
        const uint4* srcw = (const uint4*)W1;
        for (int i = t; i < 2048; i += 256) ((uint4*)lds)[i] = srcw[i];
        __syncthreads();
#pragma unroll
        for (int cc = 0; cc < 2; ++cc)
#pragma unroll
            for (int kk = 0; kk < 4; ++kk)
                bw1[cc][kk] = *(const bf16x8*)&lds[((w * 2 + cc) * 16 + lr) * 256 + kk * 64 + lg * 16];
        if constexpr (DUAL) {
            __syncthreads();
            const uint4* srcw2 = (const uint4*)W2;
            for (int i = t; i < 2048; i += 256) ((uint4*)lds)[i] = srcw2[i];
            __syncthreads();
#pragma unroll
            for (int cc = 0; cc < 2; ++cc)
#pragma unroll
                for (int kk = 0; kk < 4; ++kk)
                    bw2[cc][kk] = *(const bf16x8*)&lds[((w * 2 + cc) * 16 + lr) * 256 + kk * 64 + lg * 16];
        }
        __syncthreads();
    }

    const int t0 = blockIdx.x;
    const int t1 = blockIdx.x + GGRID;
    const bool has2 = (t1 < GTILES);

    f32x4 ss[2] = {}, sq[2] = {};

    uint4 st1[2], st2[2], fx[4];
    auto stage_load = [&](int tile) {
#pragma unroll
        for (int s = 0; s < 2; ++s) {
            int o = s * 4096 + t * 16;           // linear dest byte in bf16 A-region
            int po = o ^ (((o >> 8) & 7) << 4);  // pre-swizzled source byte
            int grow = tile * 32 + (po >> 8);
            if (grow > NN - 1) grow = NN - 1;
            if constexpr (F32A) {
                const char* src = (const char*)A1v + (size_t)grow * 512 + (size_t)(po & 255) * 2;
                fx[s * 2] = *(const uint4*)src;
                fx[s * 2 + 1] = *(const uint4*)(src + 16);
            } else {
                st1[s] = *(const uint4*)((const char*)A1v + (size_t)grow * 256 + (po & 255));
            }
            if constexpr (DUAL)
                st2[s] = *(const uint4*)((const char*)A2g + (size_t)grow * 256 + (po & 255));
        }
    };
    auto stage_write = [&](int buf) {
        char* base = lds + buf * BUFSZ;
#pragma unroll
        for (int s = 0; s < 2; ++s) {
            int o = s * 4096 + t * 16;
            uint4 v;
            if constexpr (F32A) {
                uint4 a = fx[s * 2], b2 = fx[s * 2 + 1];
                v.x = packbf(__uint_as_float(a.x), __uint_as_float(a.y));
                v.y = packbf(__uint_as_float(a.z), __uint_as_float(a.w));
                v.z = packbf(__uint_as_float(b2.x), __uint_as_float(b2.y));
                v.w = packbf(__uint_as_float(b2.z), __uint_as_float(b2.w));
            } else {
                v = st1[s];
            }
            *(uint4*)(base + o) = v;
            if constexpr (DUAL) {
                int po = o ^ (((o >> 8) & 7) << 4);
                int col0 = (po & 255) >> 1;  // 8 consecutive cols
                float4 sa = *(const float4*)&bnp[col0];
                float4 sb = *(const float4*)&bnp[col0 + 4];
                float4 ba = *(const float4*)&bnp[HD + col0];
                float4 bb2 = *(const float4*)&bnp[HD + col0 + 4];
                uint4 h;
                h.x = packbf(fmaxf(bflo(st2[s].x) * sa.x + ba.x, 0.f),
                             fmaxf(bfhi(st2[s].x) * sa.y + ba.y, 0.f));
                h.y = packbf(fmaxf(bflo(st2[s].y) * sa.z + ba.z, 0.f),
                             fmaxf(bfhi(st2[s].y) * sa.w + ba.w, 0.f));
                h.z = packbf(fmaxf(bflo(st2[s].z) * sb.x + bb2.x, 0.f),
                             fmaxf(bfhi(st2[s].z) * sb.y + bb2.y, 0.f));
                h.w = packbf(fmaxf(bflo(st2[s].w) * sb.z + bb2.z, 0.f),
                             fmaxf(bfhi(st2[s].w) * sb.w + bb2.w, 0.f));
                *(uint4*)(base + 8192 + o) = h;
            }
        }
    };
    auto compute = [&](int tile, int buf) {
        const char* base = lds + buf * BUFSZ;
        f32x4 acc[2][2] = {};
#pragma unroll
        for (int rf = 0; rf < 2; ++rf) {
            int rowb = (rf * 16 + lr) * 256;
            int sw = (lr & 7) << 4;
            bf16x8 a1[4], a2[4];
#pragma unroll
            for (int kk = 0; kk < 4; ++kk) {
                int q = rowb + ((kk * 64 + lg * 16) ^ sw);
                a1[kk] = *(const bf16x8*)(base + q);
                if constexpr (DUAL) a2[kk] = *(const bf16x8*)(base + 8192 + q);
            }
#pragma unroll
            for (int kk = 0; kk < 4; ++kk)
#pragma unroll
                for (int cc = 0; cc < 2; ++cc) {
                    acc[rf][cc] = __builtin_amdgcn_mfma_f32_16x16x32_bf16(bw1[cc][kk], a1[kk], acc[rf][cc], 0, 0, 0);
                    if constexpr (DUAL)
                        acc[rf][cc] = __builtin_amdgcn_mfma_f32_16x16x32_bf16(bw2[cc][kk], a2[kk], acc[rf][cc], 0, 0, 0);
                }
        }
#pragma unroll
        for (int rf = 0; rf < 2; ++rf) {
            int row = tile * 32 + rf * 16 + lr;
            if (row < NN) {
#pragma unroll
                for (int cc = 0; cc < 2; ++cc) {
                    f32x4 v = acc[rf][cc];
                    uint2 o;
                    o.x = packbf(v[0], v[1]);
                    o.y = packbf(v[2], v[3]);
                    *(uint2*)&Y[(size_t)row * HD + (w * 2 + cc) * 16 + lg * 4] = o;
                    ss[cc] += v;
                    sq[cc] += v * v;
                }
            }
        }
    };

    // ---- pipeline: stage t0; issue t1 loads; compute t0 (t1 in flight); write t1; compute ----
    stage_load(t0);
    stage_write(0);
    if (has2) stage_load(t1);  // in flight during compute(t0)
    __syncthreads();
    compute(t0, 0);
    if (has2) {
        stage_write(1);
        __syncthreads();
        compute(t1, 1);
    }

    // ---- stat partials: reduce over the 16 lr lanes (rows), write parts[col][bid] ----
#pragma unroll
    for (int cc = 0; cc < 2; ++cc)
#pragma unroll
        for (int j = 0; j < 4; ++j) {
            float a = ss[cc][j], b = sq[cc][j];
#pragma unroll
            for (int m = 1; m < 16; m <<= 1) {
                a += __shfl_xor(a, m);
                b += __shfl_xor(b, m);
            }
            if (lr == 0) {
                int col = (w * 2 + cc) * 16 + lg * 4 + j;
                parts[(size_t)col * GGRID + blockIdx.x] = a;
                parts[(size_t)(HD + col) * GGRID + blockIdx.x] = b;
            }
        }
}

// ---------------- BN fold v2: block j reduces 782 partials for col j -> bnp ----------------
__global__ __launch_bounds__(256) void bn_fold2(const float* __restrict__ parts,
                                                const float* __restrict__ scale,
                                                const float* __restrict__ bias,
                                                float* __restrict__ bnp) {
    __shared__ float r1[256], r2[256];
    int j = blockIdx.x;   // 0..127 column
    int t = threadIdx.x;  // 256
    float a = 0.f, b = 0.f;
    for (int i = t; i < GGRID; i += 256) {
        a += parts[(size_t)j * GGRID + i];
        b += parts[(size_t)(HD + j) * GGRID + i];
    }
    r1[t] = a; r2[t] = b;
    __syncthreads();
    for (int o = 128; o; o >>= 1) {
        if (t < o) { r1[t] += r1[t + o]; r2[t] += r2[t + o]; }
        __syncthreads();
    }
    if (t == 0) {
        float mu = r1[0] * (1.0f / NN);
        float var = r2[0] * (1.0f / NN) - mu * mu;
        float sc = scale[j] * rsqrtf(var + BN_EPS);
        bnp[j] = sc;
        bnp[HD + j] = bias[j] - mu * sc;
    }
}

// ---------------- aggregation v3: BN+ReLU fused on gathered pre-BN rows ----------------
__global__ __launch_bounds__(256) void agg_kernel(const ushort* __restrict__ Hp,
                                                  const float* __restrict__ bnp,
                                                  const int* __restrict__ adj,
                                                  const int* __restrict__ rowptr,
                                                  const float* __restrict__ invdeg,
                                                  ushort* __restrict__ A) {
    int node = blockIdx.x * 4 + (threadIdx.x >> 6);
    if (node >= NN) return;
    int l = threadIdx.x & 63;
    int slot = l >> 4, col = l & 15;
    float sc[8], bi[8];
    {
        float4 a = *(const float4*)&bnp[col * 8];
        float4 b = *(const float4*)&bnp[col * 8 + 4];
        float4 c = *(const float4*)&bnp[HD + col * 8];
        float4 d = *(const float4*)&bnp[HD + col * 8 + 4];
        sc[0] = a.x; sc[1] = a.y; sc[2] = a.z; sc[3] = a.w;
        sc[4] = b.x; sc[5] = b.y; sc[6] = b.z; sc[7] = b.w;
        bi[0] = c.x; bi[1] = c.y; bi[2] = c.z; bi[3] = c.w;
        bi[4] = d.x; bi[5] = d.y; bi[6] = d.z; bi[7] = d.w;
    }
    int b = rowptr[node], e = rowptr[node + 1];
    float id = invdeg[node];
    float acc[8] = {};
    for (int i = b; i < e; i += 8) {
        int i0 = i + slot, i1 = i + 4 + slot;
        bool v0 = i0 < e, v1 = i1 < e;
        int s0 = adj[v0 ? i0 : i];
        int s1 = adj[v1 ? i1 : i];
        uint4 a = *(const uint4*)&Hp[(size_t)s0 * HD + col * 8];
        uint4 c = *(const uint4*)&Hp[(size_t)s1 * HD + col * 8];
        float m0 = v0 ? 1.f : 0.f, m1 = v1 ? 1.f : 0.f;
        acc[0] += fmaxf(bflo(a.x) * sc[0] + bi[0], 0.f) * m0 + fmaxf(bflo(c.x) * sc[0] + bi[0], 0.f) * m1;
        acc[1] += fmaxf(bfhi(a.x) * sc[1] + bi[1], 0.f) * m0 + fmaxf(bfhi(c.x) * sc[1] + bi[1], 0.f) * m1;
        acc[2] += fmaxf(bflo(a.y) * sc[2] + bi[2], 0.f) * m0 + fmaxf(bflo(c.y) * sc[2] + bi[2], 0.f) * m1;
        acc[3] += fmaxf(bfhi(a.y) * sc[3] + bi[3], 0.f) * m0 + fmaxf(bfhi(c.y) * sc[3] + bi[3], 0.f) * m1;
        acc[4] += fmaxf(bflo(a.z) * sc[4] + bi[4], 0.f) * m0 + fmaxf(bflo(c.z) * sc[4] + bi[4], 0.f) * m1;
        acc[5] += fmaxf(bfhi(a.z) * sc[5] + bi[5], 0.f) * m0 + fmaxf(bfhi(c.z) * sc[5] + bi[5], 0.f) * m1;
        acc[6] += fmaxf(bflo(a.w) * sc[6] + bi[6], 0.f) * m0 + fmaxf(bflo(c.w) * sc[6] + bi[6], 0.f) * m1;
        acc[7] += fmaxf(bfhi(a.w) * sc[7] + bi[7], 0.f) * m0 + fmaxf(bfhi(c.w) * sc[7] + bi[7], 0.f) * m1;
    }
#pragma unroll
    for (int c2 = 0; c2 < 8; ++c2) {
        acc[c2] += __shfl_xor(acc[c2], 16);
        acc[c2] += __shfl_xor(acc[c2], 32);
    }
    if (slot == 0) {
        uint4 o;
        o.x = packbf(acc[0] * id, acc[1] * id);
        o.y = packbf(acc[2] * id, acc[3] * id);
        o.z = packbf(acc[4] * id, acc[5] * id);
        o.w = packbf(acc[6] * id, acc[7] * id);
        *(uint4*)&A[(size_t)node * HD + col * 8] = o;
    }
}

// ---------------- output: MFMA with fused BN on staging, fp32 out + bias ----------------
__global__ __launch_bounds__(256) void out_mfma(const ushort* __restrict__ Hp,
                                                const float* __restrict__ bnp,
                                                const ushort* __restrict__ W48,
                                                const float* __restrict__ B,
                                                float* __restrict__ out) {
    __shared__ __align__(16) char lds[16384];
    __shared__ float blds[48];
    const int t = threadIdx.x;
    const int l = t & 63;
    const int lr = l & 15, lg = l >> 4;
    if (t < 48) blds[t] = (t < NCLS) ? B[t] : 0.f;

    bf16x8 bw[3][4];
#pragma unroll
    for (int cc = 0; cc < 3; ++cc)
#pragma unroll
        for (int kk = 0; kk < 4; ++kk)
            bw[cc][kk] = *(const bf16x8*)&W48[(size_t)(cc * 16 + lr) * HD + kk * 32 + lg * 8];

    const int t0 = blockIdx.x, t1 = blockIdx.x + GGRID;
    const bool has2 = (t1 < GTILES);

    uint4 s1a[2];
    auto stage_load = [&](int tile) {
#pragma unroll
        for (int s = 0; s < 2; ++s) {
            int o = s * 4096 + t * 16;
            int po = o ^ (((o >> 8) & 7) << 4);
            int grow = tile * 32 + (po >> 8);
            if (grow > NN - 1) grow = NN - 1;
            s1a[s] = *(const uint4*)((const char*)Hp + (size_t)grow * 256 + (po & 255));
        }
    };
    auto stage_write = [&](int buf) {
        char* base = lds + buf * 8192;
#pragma unroll
        for (int s = 0; s < 2; ++s) {
            int o = s * 4096 + t * 16;
            int po = o ^ (((o >> 8) & 7) << 4);
            int col0 = (po & 255) >> 1;
            float4 sa = *(const float4*)&bnp[col0];
            float4 sb = *(const float4*)&bnp[col0 + 4];
            float4 ba = *(const float4*)&bnp[HD + col0];
            float4 bb2 = *(const float4*)&bnp[HD + col0 + 4];
            uint4 h;
            h.x = packbf(fmaxf(bflo(s1a[s].x) * sa.x + ba.x, 0.f),
                         fmaxf(bfhi(s1a[s].x) * sa.y + ba.y, 0.f));
            h.y = packbf(fmaxf(bflo(s1a[s].y) * sa.z + ba.z, 0.f),
                         fmaxf(bfhi(s1a[s].y) * sa.w + ba.w, 0.f));
            h.z = packbf(fmaxf(bflo(s1a[s].z) * sb.x + bb2.x, 0.f),
                         fmaxf(bfhi(s1a[s].z) * sb.y + bb2.y, 0.f));
            h.w = packbf(fmaxf(bflo(s1a[s].w) * sb.z + bb2.z, 0.f),
                         fmaxf(bfhi(s1a[s].w) * sb.w + bb2.w, 0.f));
            *(uint4*)(base + o) = h;
        }
    };
    auto compute = [&](int tile, int buf) {
        const char* base = lds + buf * 8192;
        f32x4 acc[2][3] = {};
#pragma unroll
        for (int rf = 0; rf < 2; ++rf) {
            int rowb = (rf * 16 + lr) * 256;
            int sw = (lr & 7) << 4;
            bf16x8 a1[4];
#pragma unroll
            for (int kk = 0; kk < 4; ++kk)
                a1[kk] = *(const bf16x8*)(base + rowb + ((kk * 64 + lg * 16) ^ sw));
#pragma unroll
            for (int kk = 0; kk < 4; ++kk)
#pragma unroll
                for (int cc = 0; cc < 3; ++cc)
                    acc[rf][cc] = __builtin_amdgcn_mfma_f32_16x16x32_bf16(bw[cc][kk], a1[kk], acc[rf][cc], 0, 0, 0);
        }
#pragma unroll
        for (int rf = 0; rf < 2; ++rf) {
            int row = tile * 32 + rf * 16 + lr;
            if (row < NN) {
#pragma unroll
                for (int cc = 0; cc < 3; ++cc) {
                    int col = cc * 16 + lg * 4;
                    if (col < NCLS) {
                        float4 bv = *(const float4*)&blds[col];
                        float2 lo = {acc[rf][cc][0] + bv.x, acc[rf][cc][1] + bv.y};
                        float2 hi = {acc[rf][cc][2] + bv.z, acc[rf][cc][3] + bv.w};
                        *(float2*)&out[(size_t)row * NCLS + col] = lo;
                        *(float2*)&out[(size_t)row * NCLS + col + 2] = hi;
                    }
                }
            }
        }
    };

    stage_load(t0);
    stage_write(0);
    if (has2) stage_load(t1);
    __syncthreads();
    compute(t0, 0);
    if (has2) {
        stage_write(1);
        __syncthreads();
        compute(t1, 1);
    }
}

extern "C" void kernel_launch(void* const* d_in, const int* in_sizes, int n_in,
                              void* d_out, int out_size, void* d_ws, size_t ws_size,
                              hipStream_t stream) {
    const float* x = (const float*)d_in[0];
    const void* ei = d_in[1];
    const float* fc0_w = (const float*)d_in[2];
    const float* bn_scale = (const float*)d_in[4];
    const float* bn_bias = (const float*)d_in[5];
    const float* lin_l = (const float*)d_in[6];
    const float* lin_r = (const float*)d_in[7];
    const float* W_w = (const float*)d_in[8];
    const float* out_w = (const float*)d_in[10];
    const float* out_b = (const float*)d_in[11];
    float* out = (float*)d_out;

    // ---- workspace carve-up (256B aligned) ----
    char* p = (char*)d_ws;
    auto alloc = [&](size_t bytes) -> void* {
        void* r = (void*)p;
        p += (bytes + 255) & ~(size_t)255;
        return r;
    };
    int* eflag = (int*)alloc(256);
    size_t ctrl_bytes = (size_t)(p - (char*)d_ws);
    int* rowptr = (int*)alloc((NN + 1) * 4);
    float* invdeg = (float*)alloc(NN * 4);
    int* adj = (int*)alloc(EE * 4);
    int* cnt = (int*)alloc(128 * NB * 4);
    int* boffs = (int*)alloc(128 * NB * 4);
    int* ebase = (int*)alloc((NB + 1) * 4);
    uint2* bkt = (uint2*)alloc((size_t)EE * 8);
    float* parts = (float*)alloc((size_t)256 * GGRID * 4);  // stats partials [256][782]
    float* bnp = (float*)alloc(3 * 256 * 4);        // [3][scale128|bias128]
    ushort* Wcb = (ushort*)alloc(4 * HD * HD * 2);  // [layer][l/r][128][128] bf16
    ushort* wfc0 = (ushort*)alloc(HD * HD * 2);     // fc0_w bf16
    ushort* wo48 = (ushort*)alloc(48 * HD * 2);     // out_w bf16 zero-padded to 48 rows
    ushort* hpreA = (ushort*)alloc((size_t)NN * HD * 2);  // pre-BN activations (bf16)
    ushort* hpreB = (ushort*)alloc((size_t)NN * HD * 2);
    ushort* aggb = (ushort*)alloc((size_t)NN * HD * 2);

    hipMemsetAsync(d_ws, 0, ctrl_bytes, stream);

    // graph build: detect -> hist -> offsets -> scatter -> per-bucket build
    detect_kernel<<<1, 256, 0, stream>>>(ei, eflag);
    hist_kernel<<<128, 512, 0, stream>>>(ei, eflag, cnt);
    bucket_off2<<<1, 128, 0, stream>>>(cnt, boffs, ebase);
    bucket_scatter<<<128, 512, 0, stream>>>(ei, eflag, boffs, bkt);
    bucket_build<<<NB, 512, 0, stream>>>(bkt, ebase, rowptr, invdeg, adj);

    // weights
    combine_w<<<dim3(HD, 4), HD, 0, stream>>>(W_w, lin_l, lin_r, Wcb);
    convw_kernel<<<64, 256, 0, stream>>>(fc0_w, wfc0);
    convw48<<<24, 256, 0, stream>>>(out_w, wo48);

    // fc0 (reads fp32 x directly) -> hpreA + stats (fc0_b dropped: cancelled by BN)
    gemm_mfma<false, true><<<GGRID, 256, 0, stream>>>(x, nullptr, nullptr, wfc0, nullptr, hpreA, parts);
    bn_fold2<<<128, 256, 0, stream>>>(parts, bn_scale, bn_bias, bnp);

    ushort* hcur = hpreA;
    ushort* hnext = hpreB;
    for (int layer = 0; layer < 2; ++layer) {
        float* bp = bnp + layer * 256;
        // agg applies BN+ReLU on the fly from pre-BN hcur
        agg_kernel<<<(NN + 3) / 4, 256, 0, stream>>>(hcur, bp, adj, rowptr, invdeg, aggb);
        const ushort* Wl = Wcb + (size_t)(layer * 2 + 0) * HD * HD;
        const ushort* Wr = Wcb + (size_t)(layer * 2 + 1) * HD * HD;
        // fused: hnext = bf16(aggb@Wl^T + relu(bn(hcur))@Wr^T) + stat partials
        gemm_mfma<true, false><<<GGRID, 256, 0, stream>>>(aggb, hcur, bp, Wl, Wr, hnext, parts);
        bn_fold2<<<128, 256, 0, stream>>>(parts, bn_scale + (layer + 1) * HD,
                                          bn_bias + (layer + 1) * HD, bnp + (layer + 1) * 256);
        ushort* tmp = hcur; hcur = hnext; hnext = tmp;
    }

    // out = relu(bn(hcur)) @ out_w^T + out_b  (BN fused in staging)
    out_mfma<<<GGRID, 256, 0, stream>>>(hcur, bnp + 2 * 256, wo48, out_b, out);
}